// Round 13
// baseline (359.859 us; speedup 1.0000x reference)
//
#include <hip/hip_runtime.h>
#include <stdint.h>

typedef unsigned short u16;
typedef __attribute__((ext_vector_type(4))) float f32x4;
typedef __attribute__((ext_vector_type(16))) float f32x16;
typedef __attribute__((ext_vector_type(8))) __bf16 bf16x8;
typedef __attribute__((ext_vector_type(4))) u16 u16x4;
typedef __attribute__((ext_vector_type(8))) u16 u16x8;
typedef __attribute__((ext_vector_type(4))) unsigned int u32x4;

#define S_LEN 2048
#define HIDDEN 4096
#define NHEAD 32
#define NKVH 8
#define HD 128
#define WIN 1024

__device__ __forceinline__ float bf2f(u16 u) {
  union { unsigned int i; float f; } x; x.i = ((unsigned int)u) << 16; return x.f;
}
__device__ __forceinline__ u16 f2bf(float f) {
  union { float f; unsigned int i; } x; x.f = f;
  unsigned int r = x.i + 0x7FFFu + ((x.i >> 16) & 1u);
  return (u16)(r >> 16);
}

__device__ __forceinline__ void gload16(const void* g, void* l) {
  __builtin_amdgcn_global_load_lds((const __attribute__((address_space(1))) void*)g,
                                   (__attribute__((address_space(3))) void*)l, 16, 0, 0);
}

__device__ __forceinline__ unsigned int cvtpk_bf16(float a, float b) {
  unsigned int w;
  asm("v_cvt_pk_bf16_f32 %0, %1, %2" : "=v"(w) : "v"(a), "v"(b));
  return w;
}

// ---------------- fused fp32->bf16 transpose tile (device fn, shared smem) ----------------
__device__ __forceinline__ void transp_f32(const float* __restrict__ in, int istride,
                                           u16* __restrict__ out, int ostride,
                                           int bx, int by, char* smem) {
  float (*tile)[68] = (float (*)[68])smem;  // 64x68 f32 = 17408 B
  int r0 = bx * 64, c0 = by * 64;
  int t = threadIdx.x;
  int tr = t >> 4;
  int tc = (t & 15) * 4;
#pragma unroll
  for (int i = 0; i < 4; ++i) {
    int r = i * 16 + tr;
    *(f32x4*)&tile[r][tc] = *(const f32x4*)(in + (size_t)(r0 + r) * istride + c0 + tc);
  }
  __syncthreads();
#pragma unroll
  for (int i = 0; i < 4; ++i) {
    int rr = i * 16 + tr;
    u16x4 o;
#pragma unroll
    for (int j = 0; j < 4; ++j) o[j] = f2bf(tile[tc + j][rr]);
    *(u16x4*)(out + (size_t)(c0 + rr) * ostride + r0 + tc) = o;
  }
}

// ---------------- prep: X conv + Wq/Wk/Wv transpose + bias concat (1 launch) ----------------
__global__ __launch_bounds__(256) void prep_k(const float* __restrict__ X,
                                              const float* __restrict__ Wq, const float* __restrict__ Wk,
                                              const float* __restrict__ Wv,
                                              const float* __restrict__ bq, const float* __restrict__ bk,
                                              const float* __restrict__ bv,
                                              u16* __restrict__ Xb, u16* __restrict__ WT,
                                              float* __restrict__ bqkv) {
  __shared__ __align__(16) char smem[17408];
  int bid = blockIdx.x;
  if (bid < 4096) {
    size_t i = ((size_t)bid * 256 + threadIdx.x) * 8;
    f32x4 a = *(const f32x4*)(X + i);
    f32x4 b = *(const f32x4*)(X + i + 4);
    u16x8 o;
    o[0] = f2bf(a[0]); o[1] = f2bf(a[1]); o[2] = f2bf(a[2]); o[3] = f2bf(a[3]);
    o[4] = f2bf(b[0]); o[5] = f2bf(b[1]); o[6] = f2bf(b[2]); o[7] = f2bf(b[3]);
    *(u16x8*)(Xb + i) = o;
  } else if (bid < 8192) {
    int tt = bid - 4096;
    transp_f32(Wq, 4096, WT, 4096, tt & 63, tt >> 6, smem);
  } else if (bid < 9216) {
    int tt = bid - 8192;
    transp_f32(Wk, 1024, WT + (size_t)4096 * 4096, 4096, tt & 63, tt >> 6, smem);
  } else if (bid < 10240) {
    int tt = bid - 9216;
    transp_f32(Wv, 1024, WT + (size_t)5120 * 4096, 4096, tt & 63, tt >> 6, smem);
  } else {
    int i = (bid - 10240) * 256 + threadIdx.x;
    float v = (i < 4096) ? bq[i] : (i < 5120 ? bk[i - 4096] : bv[i - 5120]);
    bqkv[i] = v;
  }
}

// ---------------- mid: RoPE/scatter + V-frag + Wo transpose (1 launch, after QKV GEMM) ----------------
__global__ __launch_bounds__(256) void mid_k(const u16* __restrict__ qkv, const int* __restrict__ pos,
                                             const float* __restrict__ cosT, const float* __restrict__ sinT,
                                             u16* __restrict__ Q, u16* __restrict__ Kf, u16* __restrict__ Vf,
                                             const float* __restrict__ Wo, u16* __restrict__ WT) {
  __shared__ __align__(16) char smem[17408];
  int bid = blockIdx.x;
  if (bid < 20480) {
    int p = bid * 256 + threadIdx.x;
    int s = p / 2560;
    int rem = p - s * 2560;
    int hs = rem >> 6;
    int d = rem & 63;
    int ps = pos[s];
    const float* cb = cosT + (size_t)ps * 128;
    const float* sb = sinT + (size_t)ps * 128;
    float c0 = cb[d], c1 = cb[d + 64], s0 = sb[d], s1 = sb[d + 64];
    if (hs < NHEAD) {
      const u16* src = qkv + (size_t)s * 6144 + hs * 128;
      float x0 = bf2f(src[d]), x1 = bf2f(src[d + 64]);
      const float qs = 0.08838834764831845f;  // 1/sqrt(128)
      u16* dst = Q + ((size_t)hs * S_LEN + s) * HD;
      dst[d] = f2bf((x0 * c0 - x1 * s0) * qs);
      dst[d + 64] = f2bf((x1 * c1 + x0 * s1) * qs);
    } else {
      int kh = hs - NHEAD;
      const u16* src = qkv + (size_t)s * 6144 + 4096 + kh * 128;
      float x0 = bf2f(src[d]), x1 = bf2f(src[d + 64]);
      int t = s >> 5, cr = s & 31;
      int ks = d >> 4, hi2 = (d >> 3) & 1, j = d & 7;
      size_t base = ((size_t)(kh * 64 + t) * 8 + ks) * 512 + (size_t)(cr + 32 * hi2) * 8 + j;
      Kf[base] = f2bf(x0 * c0 - x1 * s0);
      Kf[base + 4 * 512] = f2bf(x1 * c1 + x0 * s1);
    }
  } else if (bid < 20992) {
    // V -> MFMA-fragment-packed: lane l elem j = V[t*32 + sl*16 + (l>>5)*8 + j][dt*32 + (l&31)]
    u16 (*tile)[136] = (u16 (*)[136])smem;  // 272B rows keep 16B stores aligned
    int b2 = bid - 20480;
    int kh = b2 >> 6, t = b2 & 63;
    int tid = threadIdx.x;
#pragma unroll
    for (int i = 0; i < 2; ++i) {
      int c = tid + i * 256;
      int r = c >> 4, seg = c & 15;
      *(u16x8*)&tile[r][seg * 8] =
          *(const u16x8*)(qkv + (size_t)(t * 32 + r) * 6144 + 5120 + kh * 128 + seg * 8);
    }
    __syncthreads();
#pragma unroll
    for (int i = 0; i < 2; ++i) {
      int pp = tid + i * 256;
      int dt = pp >> 7, sl = (pp >> 6) & 1, l = pp & 63;
      int c2 = l & 31, h2 = l >> 5;
      u16x8 o;
#pragma unroll
      for (int j = 0; j < 8; ++j) o[j] = tile[sl * 16 + h2 * 8 + j][dt * 32 + c2];
      *(u16x8*)(Vf + ((size_t)(kh * 512 + t * 8 + dt * 2 + sl)) * 512 + (size_t)l * 8) = o;
    }
  } else {
    int tt = bid - 20992;
    transp_f32(Wo, 4096, WT, 4096, tt & 63, tt >> 6, smem);
  }
}

// ---------------- Pipelined GEMM v4: 4-wave blocks (r9-verified structure) ----------------
// BK=32, 256 threads (4 waves, 2x2), wave-out (BM/2)x(BN/2). Ring-3 LDS; tile t+2 staged at
// top of tile t (2-tile slack); counted vmcnt(NL) per K-tile (never 0 in-loop). Cross-block
// overlap (2-3 blocks/CU) hides the per-block barrier drain (m114 mechanism).
// XOR chunk swizzle chunk^=(cl>>1)&3 (inverse on global source, forward on ds_read) -> 0 conflicts.
template <int BM, int BN, int MINW, typename TOUT>
__global__ __launch_bounds__(256, MINW) void gemm4_k(const u16* __restrict__ A, const u16* __restrict__ Bt,
                                                     const float* __restrict__ bias, TOUT* __restrict__ C,
                                                     int M, int N, int K) {
  constexpr int WM = BM / 2, WN = BN / 2;
  constexpr int MRA = WM / 16, MRB = WN / 16;
  constexpr int NA = BM / 64, NB = BN / 64;
  constexpr int NL = NA + NB;              // gload16 per thread per K-tile (64-row units)
  __shared__ __align__(16) u16 SA[3 * BM * 32];
  __shared__ __align__(16) u16 SB[3 * BN * 32];

  int tid = threadIdx.x;
  int w = tid >> 6, l = tid & 63;
  int cl = l & 15, g = l >> 4;
  int wr = w >> 1, wc = w & 1;

  int cpx = gridDim.x >> 3;  // XCD-bijective swizzle (grid % 8 == 0)
  int wg = (blockIdx.x & 7) * cpx + (blockIdx.x >> 3);
  int nbm = M / BM;
  int bm = wg % nbm, bn = wg / nbm;

  const u16* Ag = A + (size_t)(bm * BM) * K;
  const u16* Bg = Bt + (size_t)(bn * BN) * K;
  int srow = w * 16 + (l >> 2);                  // staging row within a 64-row unit
  int csrc = ((l & 3) ^ ((l >> 3) & 3)) * 8;     // inverse-swizzled global k-chunk
  int rdc = (g ^ ((cl >> 1) & 3)) << 3;          // forward swizzle on fragment ds_read

  f32x4 acc[MRA][MRB] = {};
  int NT = K >> 5;

  auto stage = [&](int slot, int tt, int h) {
    if (h < NA) {
      gload16(Ag + (size_t)(h * 64 + srow) * K + tt * 32 + csrc,
              (void*)(SA + slot * (BM * 32) + (h * 64 + w * 16) * 32));
    } else {
      int hb = h - NA;
      gload16(Bg + (size_t)(hb * 64 + srow) * K + tt * 32 + csrc,
              (void*)(SB + slot * (BN * 32) + (hb * 64 + w * 16) * 32));
    }
  };

  // prologue: stage tiles 0 and 1
#pragma unroll
  for (int h = 0; h < NL; ++h) stage(0, 0, h);
#pragma unroll
  for (int h = 0; h < NL; ++h) stage(1, 1, h);

  for (int t = 0; t < NT; ++t) {
    // tile t's NL loads complete (tile t+1's NL stay in flight; never drain to 0 in-loop)
    if constexpr (NL == 5) asm volatile("s_waitcnt vmcnt(5)" ::: "memory");
    else if constexpr (NL == 4) asm volatile("s_waitcnt vmcnt(4)" ::: "memory");
    else asm volatile("s_waitcnt vmcnt(3)" ::: "memory");
    __builtin_amdgcn_s_barrier();
    asm volatile("" ::: "memory");

    int slot = t % 3, ss = (t + 2) % 3;
    int ts = t + 2; if (ts >= NT) ts -= NT;  // dummy wrap keeps vmcnt accounting uniform
#pragma unroll
    for (int h = 0; h < NL; ++h) stage(ss, ts, h);

    const u16* sa = SA + slot * (BM * 32);
    const u16* sb = SB + slot * (BN * 32);
    bf16x8 af[MRA], bf[MRB];
#pragma unroll
    for (int mi = 0; mi < MRA; ++mi)
      af[mi] = *(const bf16x8*)(sa + (wr * WM + mi * 16 + cl) * 32 + rdc);
#pragma unroll
    for (int ni = 0; ni < MRB; ++ni)
      bf[ni] = *(const bf16x8*)(sb + (wc * WN + ni * 16 + cl) * 32 + rdc);
    __builtin_amdgcn_s_setprio(1);
#pragma unroll
    for (int mi = 0; mi < MRA; ++mi)
#pragma unroll
      for (int ni = 0; ni < MRB; ++ni)
        acc[mi][ni] = __builtin_amdgcn_mfma_f32_16x16x32_bf16(af[mi], bf[ni], acc[mi][ni], 0, 0, 0);
    __builtin_amdgcn_s_setprio(0);
  }

  asm volatile("s_waitcnt vmcnt(0)" ::: "memory");  // drain trailing dummy stages

#pragma unroll
  for (int mi = 0; mi < MRA; ++mi) {
    int row0 = bm * BM + wr * WM + mi * 16 + g * 4;
#pragma unroll
    for (int ni = 0; ni < MRB; ++ni) {
      int col = bn * BN + wc * WN + ni * 16 + cl;
      float bb = bias[col];
      f32x4 a = acc[mi][ni];
#pragma unroll
      for (int r = 0; r < 4; ++r) {
        float v = a[r] + bb;
        if constexpr (sizeof(TOUT) == 2) C[(size_t)(row0 + r) * N + col] = f2bf(v);
        else C[(size_t)(row0 + r) * N + col] = v;
      }
    }
  }
}

// ---------------- flash attention: swapped-QK^T 32x32, in-register softmax ----------------
// No LDS -> occupancy is VGPR-bound. Register diet (single QK chain, no K prefetch,
// per-dt V loads) + launch_bounds(256,3) -> 12 waves/CU (was 8): more TLP on a
// latency-bound kernel. qb interleave-remap balances per-CU work.
__global__ __launch_bounds__(256, 3) void attn_k(const u16* __restrict__ Q, const u16* __restrict__ Kf,
                                                 const u16* __restrict__ Vf, u16* __restrict__ O) {
  int l = threadIdx.x & 63, w = threadIdx.x >> 6;
  int col = l & 31, hi = l >> 5;
  int bid = blockIdx.x;
  int kh = bid & 7;
  int head = (bid >> 3) & 3;
  int qbp = bid >> 5;
  int qb = (qbp & 1) ? (15 - (qbp >> 1)) : (qbp >> 1);  // {0,15,1,14,...}: heavy+light pairing
  int h = kh * 4 + head;
  int q0 = qb * 128 + w * 32;

  bf16x8 qf[8];
  const u16* qbase = Q + ((size_t)h * S_LEN + q0 + col) * HD + hi * 8;
#pragma unroll
  for (int ks = 0; ks < 8; ++ks) qf[ks] = *(const bf16x8*)(qbase + ks * 16);

  f32x16 ot[4];
#pragma unroll
  for (int dt = 0; dt < 4; ++dt)
#pragma unroll
    for (int r = 0; r < 16; ++r) ot[dt][r] = 0.f;
  float m_r = -3.0e38f, l_r = 0.f;

  const u16* kf0 = Kf + (size_t)kh * 64 * 4096 + (size_t)l * 8;
  const u16* vf0 = Vf + (size_t)kh * 512 * 512 + (size_t)l * 8;

  int jstart = q0 >= WIN ? q0 - WIN : 0;
  for (int j0 = jstart; j0 <= q0; j0 += 32) {
    int t = j0 >> 5;
    const u16* kb = kf0 + (size_t)t * 4096;
    f32x16 s = {};
#pragma unroll
    for (int ks = 0; ks < 8; ++ks) {
      bf16x8 kfr = *(const bf16x8*)(kb + ks * 512);
      s = __builtin_amdgcn_mfma_f32_32x32x16_bf16(kfr, qf[ks], s, 0, 0, 0);
    }

    if (j0 + 31 > q0 || j0 < q0 - 992) {
      int q = q0 + col;
#pragma unroll
      for (int r = 0; r < 16; ++r) {
        int kv = j0 + (r & 3) + 8 * (r >> 2) + 4 * hi;
        if (kv > q || kv <= q - WIN) s[r] = -3.0e38f;
      }
    }
    float vm = fmaxf(fmaxf(fmaxf(s[0], s[1]), fmaxf(s[2], s[3])),
                     fmaxf(fmaxf(s[4], s[5]), fmaxf(s[6], s[7])));
    vm = fmaxf(vm, fmaxf(fmaxf(fmaxf(s[8], s[9]), fmaxf(s[10], s[11])),
                         fmaxf(fmaxf(s[12], s[13]), fmaxf(s[14], s[15]))));
    vm = fmaxf(vm, __shfl_xor(vm, 32));
    float mnew = fmaxf(m_r, vm);
    float sc = __expf(m_r - mnew);
    m_r = mnew;
    float rs = 0.f;
#pragma unroll
    for (int r = 0; r < 16; ++r) {
      float pv = __expf(s[r] - mnew);
      s[r] = pv;
      rs += pv;
    }
    rs += __shfl_xor(rs, 32);
    l_r = l_r * sc + rs;
#pragma unroll
    for (int dt = 0; dt < 4; ++dt)
#pragma unroll
      for (int r = 0; r < 16; ++r) ot[dt][r] *= sc;

    bf16x8 pb[2];
#pragma unroll
    for (int sl = 0; sl < 2; ++sl) {
      int b = sl * 8;
      unsigned int a0 = cvtpk_bf16(s[b + 0], s[b + 1]);
      unsigned int c0 = cvtpk_bf16(s[b + 4], s[b + 5]);
      asm("v_permlane32_swap_b32 %0, %1" : "+v"(a0), "+v"(c0));
      unsigned int a1 = cvtpk_bf16(s[b + 2], s[b + 3]);
      unsigned int c1 = cvtpk_bf16(s[b + 6], s[b + 7]);
      asm("v_permlane32_swap_b32 %0, %1" : "+v"(a1), "+v"(c1));
      u32x4 pv = {a0, a1, c0, c1};
      pb[sl] = __builtin_bit_cast(bf16x8, pv);
    }
    const u16* vb = vf0 + (size_t)t * 4096;
#pragma unroll
    for (int dt = 0; dt < 4; ++dt) {
      bf16x8 v0 = *(const bf16x8*)(vb + (dt * 2 + 0) * 512);
      bf16x8 v1 = *(const bf16x8*)(vb + (dt * 2 + 1) * 512);
      ot[dt] = __builtin_amdgcn_mfma_f32_32x32x16_bf16(v0, pb[0], ot[dt], 0, 0, 0);
      ot[dt] = __builtin_amdgcn_mfma_f32_32x32x16_bf16(v1, pb[1], ot[dt], 0, 0, 0);
    }
  }

  float inv = 1.0f / l_r;
#pragma unroll
  for (int dt = 0; dt < 4; ++dt) {
#pragma unroll
    for (int g2 = 0; g2 < 4; ++g2) {
      u16x4 o;
#pragma unroll
      for (int i = 0; i < 4; ++i) o[i] = f2bf(ot[dt][g2 * 4 + i] * inv);
      *(u16x4*)(O + (size_t)(q0 + col) * HIDDEN + h * HD + dt * 32 + g2 * 8 + hi * 4) = o;
    }
  }
}

extern "C" void kernel_launch(void* const* d_in, const int* in_sizes, int n_in,
                              void* d_out, int out_size, void* d_ws, size_t ws_size,
                              hipStream_t stream) {
  const float* X = (const float*)d_in[0];
  const int* pos = (const int*)d_in[2];
  const float* cosT = (const float*)d_in[3];
  const float* sinT = (const float*)d_in[4];
  const float* Wq = (const float*)d_in[5];
  const float* bq = (const float*)d_in[6];
  const float* Wk = (const float*)d_in[7];
  const float* bk = (const float*)d_in[8];
  const float* Wv = (const float*)d_in[9];
  const float* bv = (const float*)d_in[10];
  const float* Wo = (const float*)d_in[11];
  const float* bo = (const float*)d_in[12];
  float* out = (float*)d_out;

  const size_t MB = 1ull << 20;
  char* ws = (char*)d_ws;
  u16* WT = (u16*)ws;                     // 48MB: Wqkv^T bf16; later Wo^T (written in mid_k)
  u16* Xb = (u16*)(ws + 48 * MB);         // 16MB: X bf16; later Q [32][2048][128]
  u16* Qs = Xb;
  u16* QKVr = (u16*)(ws + 64 * MB);       // 24MB: QKV raw [2048][6144]; later attnO [2048][4096]
  u16* attnO = QKVr;
  u16* Kfr = (u16*)(ws + 88 * MB);        // 4MB: K fragment-packed
  u16* Vfr = (u16*)(ws + 92 * MB);        // 4MB: V fragment-packed
  float* bqkv = (float*)(ws + 96 * MB);   // 24KB

  // prep: conv + Wq/Wk/Wv transposes + bias concat (fused, 1 launch)
  prep_k<<<10264, 256, 0, stream>>>(X, Wq, Wk, Wv, bq, bk, bv, Xb, WT, bqkv);

  // QKV: 128x128 tiles, 4 waves, 48KB LDS -> 3 blocks/CU, 768 WGs (exactly 3/CU)
  gemm4_k<128, 128, 3, u16><<<768, 256, 0, stream>>>(Xb, WT, bqkv, QKVr, 2048, 6144, 4096);

  // mid: rope/scatter + vfrag + Wo^T (fused, 1 launch; Wqkv^T dead after QKV GEMM)
  mid_k<<<25088, 256, 0, stream>>>(QKVr, pos, cosT, sinT, Qs, Kfr, Vfr, Wo, WT);

  attn_k<<<512, 256, 0, stream>>>(Qs, Kfr, Vfr, attnO);

  // out-proj: 128x128 tiles, 512 WGs (2/CU balanced) — r11 best-measured config
  gemm4_k<128, 128, 3, float><<<512, 256, 0, stream>>>(attnO, WT, bo, out, 2048, 4096, 4096);
}

// Round 14
// 329.539 us; speedup vs baseline: 1.0920x; 1.0920x over previous
//
#include <hip/hip_runtime.h>
#include <stdint.h>

typedef unsigned short u16;
typedef __attribute__((ext_vector_type(4))) float f32x4;
typedef __attribute__((ext_vector_type(16))) float f32x16;
typedef __attribute__((ext_vector_type(8))) __bf16 bf16x8;
typedef __attribute__((ext_vector_type(4))) u16 u16x4;
typedef __attribute__((ext_vector_type(8))) u16 u16x8;
typedef __attribute__((ext_vector_type(4))) unsigned int u32x4;

#define S_LEN 2048
#define HIDDEN 4096
#define NHEAD 32
#define NKVH 8
#define HD 128
#define WIN 1024

__device__ __forceinline__ float bf2f(u16 u) {
  union { unsigned int i; float f; } x; x.i = ((unsigned int)u) << 16; return x.f;
}
__device__ __forceinline__ u16 f2bf(float f) {
  union { float f; unsigned int i; } x; x.f = f;
  unsigned int r = x.i + 0x7FFFu + ((x.i >> 16) & 1u);
  return (u16)(r >> 16);
}

__device__ __forceinline__ void gload16(const void* g, void* l) {
  __builtin_amdgcn_global_load_lds((const __attribute__((address_space(1))) void*)g,
                                   (__attribute__((address_space(3))) void*)l, 16, 0, 0);
}

__device__ __forceinline__ unsigned int cvtpk_bf16(float a, float b) {
  unsigned int w;
  asm("v_cvt_pk_bf16_f32 %0, %1, %2" : "=v"(w) : "v"(a), "v"(b));
  return w;
}

// ---------------- fused fp32->bf16 transpose tile (device fn, shared smem) ----------------
__device__ __forceinline__ void transp_f32(const float* __restrict__ in, int istride,
                                           u16* __restrict__ out, int ostride,
                                           int bx, int by, char* smem) {
  float (*tile)[68] = (float (*)[68])smem;  // 64x68 f32 = 17408 B
  int r0 = bx * 64, c0 = by * 64;
  int t = threadIdx.x;
  int tr = t >> 4;
  int tc = (t & 15) * 4;
#pragma unroll
  for (int i = 0; i < 4; ++i) {
    int r = i * 16 + tr;
    *(f32x4*)&tile[r][tc] = *(const f32x4*)(in + (size_t)(r0 + r) * istride + c0 + tc);
  }
  __syncthreads();
#pragma unroll
  for (int i = 0; i < 4; ++i) {
    int rr = i * 16 + tr;
    u16x4 o;
#pragma unroll
    for (int j = 0; j < 4; ++j) o[j] = f2bf(tile[tc + j][rr]);
    *(u16x4*)(out + (size_t)(c0 + rr) * ostride + r0 + tc) = o;
  }
}

// ---------------- prep: X conv + Wq/Wk/Wv transpose + bias concat (1 launch) ----------------
__global__ __launch_bounds__(256) void prep_k(const float* __restrict__ X,
                                              const float* __restrict__ Wq, const float* __restrict__ Wk,
                                              const float* __restrict__ Wv,
                                              const float* __restrict__ bq, const float* __restrict__ bk,
                                              const float* __restrict__ bv,
                                              u16* __restrict__ Xb, u16* __restrict__ WT,
                                              float* __restrict__ bqkv) {
  __shared__ __align__(16) char smem[17408];
  int bid = blockIdx.x;
  if (bid < 4096) {
    size_t i = ((size_t)bid * 256 + threadIdx.x) * 8;
    f32x4 a = *(const f32x4*)(X + i);
    f32x4 b = *(const f32x4*)(X + i + 4);
    u16x8 o;
    o[0] = f2bf(a[0]); o[1] = f2bf(a[1]); o[2] = f2bf(a[2]); o[3] = f2bf(a[3]);
    o[4] = f2bf(b[0]); o[5] = f2bf(b[1]); o[6] = f2bf(b[2]); o[7] = f2bf(b[3]);
    *(u16x8*)(Xb + i) = o;
  } else if (bid < 8192) {
    int tt = bid - 4096;
    transp_f32(Wq, 4096, WT, 4096, tt & 63, tt >> 6, smem);
  } else if (bid < 9216) {
    int tt = bid - 8192;
    transp_f32(Wk, 1024, WT + (size_t)4096 * 4096, 4096, tt & 63, tt >> 6, smem);
  } else if (bid < 10240) {
    int tt = bid - 9216;
    transp_f32(Wv, 1024, WT + (size_t)5120 * 4096, 4096, tt & 63, tt >> 6, smem);
  } else {
    int i = (bid - 10240) * 256 + threadIdx.x;
    float v = (i < 4096) ? bq[i] : (i < 5120 ? bk[i - 4096] : bv[i - 5120]);
    bqkv[i] = v;
  }
}

// ---------------- mid: RoPE/scatter + V-frag + Wo transpose (1 launch, after QKV GEMM) ----------------
__global__ __launch_bounds__(256) void mid_k(const u16* __restrict__ qkv, const int* __restrict__ pos,
                                             const float* __restrict__ cosT, const float* __restrict__ sinT,
                                             u16* __restrict__ Q, u16* __restrict__ Kf, u16* __restrict__ Vf,
                                             const float* __restrict__ Wo, u16* __restrict__ WT) {
  __shared__ __align__(16) char smem[17408];
  int bid = blockIdx.x;
  if (bid < 20480) {
    int p = bid * 256 + threadIdx.x;
    int s = p / 2560;
    int rem = p - s * 2560;
    int hs = rem >> 6;
    int d = rem & 63;
    int ps = pos[s];
    const float* cb = cosT + (size_t)ps * 128;
    const float* sb = sinT + (size_t)ps * 128;
    float c0 = cb[d], c1 = cb[d + 64], s0 = sb[d], s1 = sb[d + 64];
    if (hs < NHEAD) {
      const u16* src = qkv + (size_t)s * 6144 + hs * 128;
      float x0 = bf2f(src[d]), x1 = bf2f(src[d + 64]);
      const float qs = 0.08838834764831845f;  // 1/sqrt(128)
      u16* dst = Q + ((size_t)hs * S_LEN + s) * HD;
      dst[d] = f2bf((x0 * c0 - x1 * s0) * qs);
      dst[d + 64] = f2bf((x1 * c1 + x0 * s1) * qs);
    } else {
      int kh = hs - NHEAD;
      const u16* src = qkv + (size_t)s * 6144 + 4096 + kh * 128;
      float x0 = bf2f(src[d]), x1 = bf2f(src[d + 64]);
      int t = s >> 5, cr = s & 31;
      int ks = d >> 4, hi2 = (d >> 3) & 1, j = d & 7;
      size_t base = ((size_t)(kh * 64 + t) * 8 + ks) * 512 + (size_t)(cr + 32 * hi2) * 8 + j;
      Kf[base] = f2bf(x0 * c0 - x1 * s0);
      Kf[base + 4 * 512] = f2bf(x1 * c1 + x0 * s1);
    }
  } else if (bid < 20992) {
    // V -> MFMA-fragment-packed: lane l elem j = V[t*32 + sl*16 + (l>>5)*8 + j][dt*32 + (l&31)]
    u16 (*tile)[136] = (u16 (*)[136])smem;  // 272B rows keep 16B stores aligned
    int b2 = bid - 20480;
    int kh = b2 >> 6, t = b2 & 63;
    int tid = threadIdx.x;
#pragma unroll
    for (int i = 0; i < 2; ++i) {
      int c = tid + i * 256;
      int r = c >> 4, seg = c & 15;
      *(u16x8*)&tile[r][seg * 8] =
          *(const u16x8*)(qkv + (size_t)(t * 32 + r) * 6144 + 5120 + kh * 128 + seg * 8);
    }
    __syncthreads();
#pragma unroll
    for (int i = 0; i < 2; ++i) {
      int pp = tid + i * 256;
      int dt = pp >> 7, sl = (pp >> 6) & 1, l = pp & 63;
      int c2 = l & 31, h2 = l >> 5;
      u16x8 o;
#pragma unroll
      for (int j = 0; j < 8; ++j) o[j] = tile[sl * 16 + h2 * 8 + j][dt * 32 + c2];
      *(u16x8*)(Vf + ((size_t)(kh * 512 + t * 8 + dt * 2 + sl)) * 512 + (size_t)l * 8) = o;
    }
  } else {
    int tt = bid - 20992;
    transp_f32(Wo, 4096, WT, 4096, tt & 63, tt >> 6, smem);
  }
}

// ---------------- Pipelined GEMM v4: 4-wave blocks (r9-verified structure) ----------------
// BK=32, 256 threads (4 waves, 2x2), wave-out (BM/2)x(BN/2). Ring-3 LDS; tile t+2 staged at
// top of tile t (2-tile slack); counted vmcnt(NL) per K-tile (never 0 in-loop). Cross-block
// overlap (2-3 blocks/CU) hides the per-block barrier drain (m114 mechanism).
// XOR chunk swizzle chunk^=(cl>>1)&3 (inverse on global source, forward on ds_read) -> 0 conflicts.
template <int BM, int BN, int MINW, typename TOUT>
__global__ __launch_bounds__(256, MINW) void gemm4_k(const u16* __restrict__ A, const u16* __restrict__ Bt,
                                                     const float* __restrict__ bias, TOUT* __restrict__ C,
                                                     int M, int N, int K) {
  constexpr int WM = BM / 2, WN = BN / 2;
  constexpr int MRA = WM / 16, MRB = WN / 16;
  constexpr int NA = BM / 64, NB = BN / 64;
  constexpr int NL = NA + NB;              // gload16 per thread per K-tile (64-row units)
  __shared__ __align__(16) u16 SA[3 * BM * 32];
  __shared__ __align__(16) u16 SB[3 * BN * 32];

  int tid = threadIdx.x;
  int w = tid >> 6, l = tid & 63;
  int cl = l & 15, g = l >> 4;
  int wr = w >> 1, wc = w & 1;

  int cpx = gridDim.x >> 3;  // XCD-bijective swizzle (grid % 8 == 0)
  int wg = (blockIdx.x & 7) * cpx + (blockIdx.x >> 3);
  int nbm = M / BM;
  int bm = wg % nbm, bn = wg / nbm;

  const u16* Ag = A + (size_t)(bm * BM) * K;
  const u16* Bg = Bt + (size_t)(bn * BN) * K;
  int srow = w * 16 + (l >> 2);                  // staging row within a 64-row unit
  int csrc = ((l & 3) ^ ((l >> 3) & 3)) * 8;     // inverse-swizzled global k-chunk
  int rdc = (g ^ ((cl >> 1) & 3)) << 3;          // forward swizzle on fragment ds_read

  f32x4 acc[MRA][MRB] = {};
  int NT = K >> 5;

  auto stage = [&](int slot, int tt, int h) {
    if (h < NA) {
      gload16(Ag + (size_t)(h * 64 + srow) * K + tt * 32 + csrc,
              (void*)(SA + slot * (BM * 32) + (h * 64 + w * 16) * 32));
    } else {
      int hb = h - NA;
      gload16(Bg + (size_t)(hb * 64 + srow) * K + tt * 32 + csrc,
              (void*)(SB + slot * (BN * 32) + (hb * 64 + w * 16) * 32));
    }
  };

  // prologue: stage tiles 0 and 1
#pragma unroll
  for (int h = 0; h < NL; ++h) stage(0, 0, h);
#pragma unroll
  for (int h = 0; h < NL; ++h) stage(1, 1, h);

  for (int t = 0; t < NT; ++t) {
    // tile t's NL loads complete (tile t+1's NL stay in flight; never drain to 0 in-loop)
    if constexpr (NL == 5) asm volatile("s_waitcnt vmcnt(5)" ::: "memory");
    else if constexpr (NL == 4) asm volatile("s_waitcnt vmcnt(4)" ::: "memory");
    else asm volatile("s_waitcnt vmcnt(3)" ::: "memory");
    __builtin_amdgcn_s_barrier();
    asm volatile("" ::: "memory");

    int slot = t % 3, ss = (t + 2) % 3;
    int ts = t + 2; if (ts >= NT) ts -= NT;  // dummy wrap keeps vmcnt accounting uniform
#pragma unroll
    for (int h = 0; h < NL; ++h) stage(ss, ts, h);

    const u16* sa = SA + slot * (BM * 32);
    const u16* sb = SB + slot * (BN * 32);
    bf16x8 af[MRA], bf[MRB];
#pragma unroll
    for (int mi = 0; mi < MRA; ++mi)
      af[mi] = *(const bf16x8*)(sa + (wr * WM + mi * 16 + cl) * 32 + rdc);
#pragma unroll
    for (int ni = 0; ni < MRB; ++ni)
      bf[ni] = *(const bf16x8*)(sb + (wc * WN + ni * 16 + cl) * 32 + rdc);
    __builtin_amdgcn_s_setprio(1);
#pragma unroll
    for (int mi = 0; mi < MRA; ++mi)
#pragma unroll
      for (int ni = 0; ni < MRB; ++ni)
        acc[mi][ni] = __builtin_amdgcn_mfma_f32_16x16x32_bf16(af[mi], bf[ni], acc[mi][ni], 0, 0, 0);
    __builtin_amdgcn_s_setprio(0);
  }

  asm volatile("s_waitcnt vmcnt(0)" ::: "memory");  // drain trailing dummy stages

#pragma unroll
  for (int mi = 0; mi < MRA; ++mi) {
    int row0 = bm * BM + wr * WM + mi * 16 + g * 4;
#pragma unroll
    for (int ni = 0; ni < MRB; ++ni) {
      int col = bn * BN + wc * WN + ni * 16 + cl;
      float bb = bias[col];
      f32x4 a = acc[mi][ni];
#pragma unroll
      for (int r = 0; r < 4; ++r) {
        float v = a[r] + bb;
        if constexpr (sizeof(TOUT) == 2) C[(size_t)(row0 + r) * N + col] = f2bf(v);
        else C[(size_t)(row0 + r) * N + col] = v;
      }
    }
  }
}

// ---------------- flash attention (r11 best-measured version) ----------------
// swapped-QK^T 32x32, in-register softmax; qb interleave-remap balances per-CU work;
// K-fragments double-buffered across KV tiles; dual-chain QK^T accumulate.
__global__ __launch_bounds__(256, 2) void attn_k(const u16* __restrict__ Q, const u16* __restrict__ Kf,
                                                 const u16* __restrict__ Vf, u16* __restrict__ O) {
  int l = threadIdx.x & 63, w = threadIdx.x >> 6;
  int col = l & 31, hi = l >> 5;
  int bid = blockIdx.x;
  int kh = bid & 7;
  int head = (bid >> 3) & 3;
  int qbp = bid >> 5;
  int qb = (qbp & 1) ? (15 - (qbp >> 1)) : (qbp >> 1);  // {0,15,1,14,...}: heavy+light pairing
  int h = kh * 4 + head;
  int q0 = qb * 128 + w * 32;

  bf16x8 qf[8];
  const u16* qbase = Q + ((size_t)h * S_LEN + q0 + col) * HD + hi * 8;
#pragma unroll
  for (int ks = 0; ks < 8; ++ks) qf[ks] = *(const bf16x8*)(qbase + ks * 16);

  f32x16 ot[4];
#pragma unroll
  for (int dt = 0; dt < 4; ++dt)
#pragma unroll
    for (int r = 0; r < 16; ++r) ot[dt][r] = 0.f;
  float m_r = -3.0e38f, l_r = 0.f;

  const u16* kf0 = Kf + (size_t)kh * 64 * 4096 + (size_t)l * 8;
  const u16* vf0 = Vf + (size_t)kh * 512 * 512 + (size_t)l * 8;

  int jstart = q0 >= WIN ? q0 - WIN : 0;
  bf16x8 kfr[8];
  {
    const u16* kb = kf0 + (size_t)(jstart >> 5) * 4096;
#pragma unroll
    for (int ks = 0; ks < 8; ++ks) kfr[ks] = *(const bf16x8*)(kb + ks * 512);
  }

  for (int j0 = jstart; j0 <= q0; j0 += 32) {
    int t = j0 >> 5;
    f32x16 sA = {}, sB = {};
#pragma unroll
    for (int ks = 0; ks < 4; ++ks)
      sA = __builtin_amdgcn_mfma_f32_32x32x16_bf16(kfr[ks], qf[ks], sA, 0, 0, 0);
#pragma unroll
    for (int ks = 4; ks < 8; ++ks)
      sB = __builtin_amdgcn_mfma_f32_32x32x16_bf16(kfr[ks], qf[ks], sB, 0, 0, 0);
    int tn = (j0 + 32 <= q0) ? (t + 1) : t;
    const u16* kbn = kf0 + (size_t)tn * 4096;
    bf16x8 kfn[8];
#pragma unroll
    for (int ks = 0; ks < 8; ++ks) kfn[ks] = *(const bf16x8*)(kbn + ks * 512);
    const u16* vb = vf0 + (size_t)t * 4096;
    bf16x8 vfr[8];
#pragma unroll
    for (int c = 0; c < 8; ++c) vfr[c] = *(const bf16x8*)(vb + c * 512);

    f32x16 s = sA + sB;

    if (j0 + 31 > q0 || j0 < q0 - 992) {
      int q = q0 + col;
#pragma unroll
      for (int r = 0; r < 16; ++r) {
        int kv = j0 + (r & 3) + 8 * (r >> 2) + 4 * hi;
        if (kv > q || kv <= q - WIN) s[r] = -3.0e38f;
      }
    }
    float vm = fmaxf(fmaxf(fmaxf(s[0], s[1]), fmaxf(s[2], s[3])),
                     fmaxf(fmaxf(s[4], s[5]), fmaxf(s[6], s[7])));
    vm = fmaxf(vm, fmaxf(fmaxf(fmaxf(s[8], s[9]), fmaxf(s[10], s[11])),
                         fmaxf(fmaxf(s[12], s[13]), fmaxf(s[14], s[15]))));
    vm = fmaxf(vm, __shfl_xor(vm, 32));
    float mnew = fmaxf(m_r, vm);
    float sc = __expf(m_r - mnew);
    m_r = mnew;
    float rs = 0.f;
#pragma unroll
    for (int r = 0; r < 16; ++r) {
      float pv = __expf(s[r] - mnew);
      s[r] = pv;
      rs += pv;
    }
    rs += __shfl_xor(rs, 32);
    l_r = l_r * sc + rs;
#pragma unroll
    for (int dt = 0; dt < 4; ++dt)
#pragma unroll
      for (int r = 0; r < 16; ++r) ot[dt][r] *= sc;

    bf16x8 pb[2];
#pragma unroll
    for (int sl = 0; sl < 2; ++sl) {
      int b = sl * 8;
      unsigned int a0 = cvtpk_bf16(s[b + 0], s[b + 1]);
      unsigned int c0 = cvtpk_bf16(s[b + 4], s[b + 5]);
      asm("v_permlane32_swap_b32 %0, %1" : "+v"(a0), "+v"(c0));
      unsigned int a1 = cvtpk_bf16(s[b + 2], s[b + 3]);
      unsigned int c1 = cvtpk_bf16(s[b + 6], s[b + 7]);
      asm("v_permlane32_swap_b32 %0, %1" : "+v"(a1), "+v"(c1));
      u32x4 pv = {a0, a1, c0, c1};
      pb[sl] = __builtin_bit_cast(bf16x8, pv);
    }
#pragma unroll
    for (int dt = 0; dt < 4; ++dt) {
      ot[dt] = __builtin_amdgcn_mfma_f32_32x32x16_bf16(vfr[dt * 2 + 0], pb[0], ot[dt], 0, 0, 0);
      ot[dt] = __builtin_amdgcn_mfma_f32_32x32x16_bf16(vfr[dt * 2 + 1], pb[1], ot[dt], 0, 0, 0);
    }
#pragma unroll
    for (int ks = 0; ks < 8; ++ks) kfr[ks] = kfn[ks];
  }

  float inv = 1.0f / l_r;
#pragma unroll
  for (int dt = 0; dt < 4; ++dt) {
#pragma unroll
    for (int g2 = 0; g2 < 4; ++g2) {
      u16x4 o;
#pragma unroll
      for (int i = 0; i < 4; ++i) o[i] = f2bf(ot[dt][g2 * 4 + i] * inv);
      *(u16x4*)(O + (size_t)(q0 + col) * HIDDEN + h * HD + dt * 32 + g2 * 8 + hi * 4) = o;
    }
  }
}

extern "C" void kernel_launch(void* const* d_in, const int* in_sizes, int n_in,
                              void* d_out, int out_size, void* d_ws, size_t ws_size,
                              hipStream_t stream) {
  const float* X = (const float*)d_in[0];
  const int* pos = (const int*)d_in[2];
  const float* cosT = (const float*)d_in[3];
  const float* sinT = (const float*)d_in[4];
  const float* Wq = (const float*)d_in[5];
  const float* bq = (const float*)d_in[6];
  const float* Wk = (const float*)d_in[7];
  const float* bk = (const float*)d_in[8];
  const float* Wv = (const float*)d_in[9];
  const float* bv = (const float*)d_in[10];
  const float* Wo = (const float*)d_in[11];
  const float* bo = (const float*)d_in[12];
  float* out = (float*)d_out;

  const size_t MB = 1ull << 20;
  char* ws = (char*)d_ws;
  u16* WT = (u16*)ws;                     // 48MB: Wqkv^T bf16; later Wo^T (written in mid_k)
  u16* Xb = (u16*)(ws + 48 * MB);         // 16MB: X bf16; later Q [32][2048][128]
  u16* Qs = Xb;
  u16* QKVr = (u16*)(ws + 64 * MB);       // 24MB: QKV raw [2048][6144]; later attnO [2048][4096]
  u16* attnO = QKVr;
  u16* Kfr = (u16*)(ws + 88 * MB);        // 4MB: K fragment-packed
  u16* Vfr = (u16*)(ws + 92 * MB);        // 4MB: V fragment-packed
  float* bqkv = (float*)(ws + 96 * MB);   // 24KB

  // prep: conv + Wq/Wk/Wv transposes + bias concat (fused, 1 launch)
  prep_k<<<10264, 256, 0, stream>>>(X, Wq, Wk, Wv, bq, bk, bv, Xb, WT, bqkv);

  // QKV: 128x128 tiles, 4 waves, 48KB LDS -> 3 blocks/CU, 768 WGs (exactly 3/CU)
  gemm4_k<128, 128, 3, u16><<<768, 256, 0, stream>>>(Xb, WT, bqkv, QKVr, 2048, 6144, 4096);

  // mid: rope/scatter + vfrag + Wo^T (fused, 1 launch; Wqkv^T dead after QKV GEMM)
  mid_k<<<25088, 256, 0, stream>>>(QKVr, pos, cosT, sinT, Qs, Kfr, Vfr, Wo, WT);

  attn_k<<<512, 256, 0, stream>>>(Qs, Kfr, Vfr, attnO);

  // out-proj: 128x128 tiles, 512 WGs (2/CU balanced) — r11 best-measured config
  gemm4_k<128, 128, 3, float><<<512, 256, 0, stream>>>(attnO, WT, bo, out, 2048, 4096, 4096);
}

// Round 15
// 321.099 us; speedup vs baseline: 1.1207x; 1.0263x over previous
//
#include <hip/hip_runtime.h>
#include <stdint.h>

typedef unsigned short u16;
typedef __attribute__((ext_vector_type(4))) float f32x4;
typedef __attribute__((ext_vector_type(16))) float f32x16;
typedef __attribute__((ext_vector_type(8))) __bf16 bf16x8;
typedef __attribute__((ext_vector_type(4))) u16 u16x4;
typedef __attribute__((ext_vector_type(8))) u16 u16x8;
typedef __attribute__((ext_vector_type(4))) unsigned int u32x4;

#define S_LEN 2048
#define HIDDEN 4096
#define NHEAD 32
#define NKVH 8
#define HD 128
#define WIN 1024

__device__ __forceinline__ float bf2f(u16 u) {
  union { unsigned int i; float f; } x; x.i = ((unsigned int)u) << 16; return x.f;
}
__device__ __forceinline__ u16 f2bf(float f) {
  union { float f; unsigned int i; } x; x.f = f;
  unsigned int r = x.i + 0x7FFFu + ((x.i >> 16) & 1u);
  return (u16)(r >> 16);
}

__device__ __forceinline__ void gload16(const void* g, void* l) {
  __builtin_amdgcn_global_load_lds((const __attribute__((address_space(1))) void*)g,
                                   (__attribute__((address_space(3))) void*)l, 16, 0, 0);
}

__device__ __forceinline__ unsigned int cvtpk_bf16(float a, float b) {
  unsigned int w;
  asm("v_cvt_pk_bf16_f32 %0, %1, %2" : "=v"(w) : "v"(a), "v"(b));
  return w;
}

// ---------------- fused fp32->bf16 transpose tile (device fn, shared smem) ----------------
__device__ __forceinline__ void transp_f32(const float* __restrict__ in, int istride,
                                           u16* __restrict__ out, int ostride,
                                           int bx, int by, char* smem) {
  float (*tile)[68] = (float (*)[68])smem;  // 64x68 f32 = 17408 B
  int r0 = bx * 64, c0 = by * 64;
  int t = threadIdx.x;
  int tr = t >> 4;
  int tc = (t & 15) * 4;
#pragma unroll
  for (int i = 0; i < 4; ++i) {
    int r = i * 16 + tr;
    *(f32x4*)&tile[r][tc] = *(const f32x4*)(in + (size_t)(r0 + r) * istride + c0 + tc);
  }
  __syncthreads();
#pragma unroll
  for (int i = 0; i < 4; ++i) {
    int rr = i * 16 + tr;
    u16x4 o;
#pragma unroll
    for (int j = 0; j < 4; ++j) o[j] = f2bf(tile[tc + j][rr]);
    *(u16x4*)(out + (size_t)(c0 + rr) * ostride + r0 + tc) = o;
  }
}

// ---------------- prep: X conv + Wq/Wk/Wv transpose + bias concat (1 launch) ----------------
__global__ __launch_bounds__(256) void prep_k(const float* __restrict__ X,
                                              const float* __restrict__ Wq, const float* __restrict__ Wk,
                                              const float* __restrict__ Wv,
                                              const float* __restrict__ bq, const float* __restrict__ bk,
                                              const float* __restrict__ bv,
                                              u16* __restrict__ Xb, u16* __restrict__ WT,
                                              float* __restrict__ bqkv) {
  __shared__ __align__(16) char smem[17408];
  int bid = blockIdx.x;
  if (bid < 4096) {
    size_t i = ((size_t)bid * 256 + threadIdx.x) * 8;
    f32x4 a = *(const f32x4*)(X + i);
    f32x4 b = *(const f32x4*)(X + i + 4);
    u16x8 o;
    o[0] = f2bf(a[0]); o[1] = f2bf(a[1]); o[2] = f2bf(a[2]); o[3] = f2bf(a[3]);
    o[4] = f2bf(b[0]); o[5] = f2bf(b[1]); o[6] = f2bf(b[2]); o[7] = f2bf(b[3]);
    *(u16x8*)(Xb + i) = o;
  } else if (bid < 8192) {
    int tt = bid - 4096;
    transp_f32(Wq, 4096, WT, 4096, tt & 63, tt >> 6, smem);
  } else if (bid < 9216) {
    int tt = bid - 8192;
    transp_f32(Wk, 1024, WT + (size_t)4096 * 4096, 4096, tt & 63, tt >> 6, smem);
  } else if (bid < 10240) {
    int tt = bid - 9216;
    transp_f32(Wv, 1024, WT + (size_t)5120 * 4096, 4096, tt & 63, tt >> 6, smem);
  } else {
    int i = (bid - 10240) * 256 + threadIdx.x;
    float v = (i < 4096) ? bq[i] : (i < 5120 ? bk[i - 4096] : bv[i - 5120]);
    bqkv[i] = v;
  }
}

// ---------------- QKV GEMM with fused RoPE/scatter epilogue ----------------
// K-loop: r9-verified gemm4 structure (BM=BN=128, 4 waves 2x2, ring-3, counted vmcnt(4),
// chunk swizzle). Epilogue: bias-added bf16 tile staged in the (dead) ring LDS, then:
//   bn<32  : Q head bn  -> RoPE + 1/sqrt(128) scale -> Q[h][s][128]
//   bn<40  : K head bn-32 -> RoPE -> Kf fragment layout (verified rope_scatter_k formula)
//   else   : V head bn-40 -> Vf fragment layout (verified vfrag_k formula)
__global__ __launch_bounds__(256, 3) void gemmqkv_k(const u16* __restrict__ A, const u16* __restrict__ Bt,
                                                    const float* __restrict__ bias,
                                                    const int* __restrict__ pos,
                                                    const float* __restrict__ cosT, const float* __restrict__ sinT,
                                                    u16* __restrict__ Q, u16* __restrict__ Kf,
                                                    u16* __restrict__ Vf, int K) {
  constexpr int NL = 4;
  __shared__ __align__(16) u16 SM[24576];  // ring: SA=SM[0..12288), SB=SM[12288..24576); epilogue tile reuses
  u16* SA = SM;
  u16* SB = SM + 12288;

  int tid = threadIdx.x;
  int w = tid >> 6, l = tid & 63;
  int cl = l & 15, g = l >> 4;
  int wr = w >> 1, wc = w & 1;

  int cpx = gridDim.x >> 3;  // XCD-bijective swizzle (grid % 8 == 0)
  int wg = (blockIdx.x & 7) * cpx + (blockIdx.x >> 3);
  int bm = wg & 15, bn = wg >> 4;  // nbm = 16

  const u16* Ag = A + (size_t)(bm * 128) * K;
  const u16* Bg = Bt + (size_t)(bn * 128) * K;
  int srow = w * 16 + (l >> 2);
  int csrc = ((l & 3) ^ ((l >> 3) & 3)) * 8;
  int rdc = (g ^ ((cl >> 1) & 3)) << 3;

  f32x4 acc[4][4] = {};
  int NT = K >> 5;

  auto stage = [&](int slot, int tt, int h) {
    if (h < 2) {
      gload16(Ag + (size_t)(h * 64 + srow) * K + tt * 32 + csrc,
              (void*)(SA + slot * 4096 + (h * 64 + w * 16) * 32));
    } else {
      int hb = h - 2;
      gload16(Bg + (size_t)(hb * 64 + srow) * K + tt * 32 + csrc,
              (void*)(SB + slot * 4096 + (hb * 64 + w * 16) * 32));
    }
  };

#pragma unroll
  for (int h = 0; h < NL; ++h) stage(0, 0, h);
#pragma unroll
  for (int h = 0; h < NL; ++h) stage(1, 1, h);

  for (int t = 0; t < NT; ++t) {
    asm volatile("s_waitcnt vmcnt(4)" ::: "memory");
    __builtin_amdgcn_s_barrier();
    asm volatile("" ::: "memory");

    int slot = t % 3, ss = (t + 2) % 3;
    int ts = t + 2; if (ts >= NT) ts -= NT;
#pragma unroll
    for (int h = 0; h < NL; ++h) stage(ss, ts, h);

    const u16* sa = SA + slot * 4096;
    const u16* sb = SB + slot * 4096;
    bf16x8 af[4], bf[4];
#pragma unroll
    for (int mi = 0; mi < 4; ++mi)
      af[mi] = *(const bf16x8*)(sa + (wr * 64 + mi * 16 + cl) * 32 + rdc);
#pragma unroll
    for (int ni = 0; ni < 4; ++ni)
      bf[ni] = *(const bf16x8*)(sb + (wc * 64 + ni * 16 + cl) * 32 + rdc);
    __builtin_amdgcn_s_setprio(1);
#pragma unroll
    for (int mi = 0; mi < 4; ++mi)
#pragma unroll
      for (int ni = 0; ni < 4; ++ni)
        acc[mi][ni] = __builtin_amdgcn_mfma_f32_16x16x32_bf16(af[mi], bf[ni], acc[mi][ni], 0, 0, 0);
    __builtin_amdgcn_s_setprio(0);
  }

  asm volatile("s_waitcnt vmcnt(0)" ::: "memory");
  __syncthreads();  // all waves done with ring before LDS reuse

  // ---- stage bias-added bf16 tile in LDS (row stride 132 breaks pow2 banks) ----
  u16 (*tileL)[132] = (u16 (*)[132])SM;
#pragma unroll
  for (int mi = 0; mi < 4; ++mi)
#pragma unroll
    for (int ni = 0; ni < 4; ++ni) {
      int col = wc * 64 + ni * 16 + cl;
      float bb = bias[bn * 128 + col];
#pragma unroll
      for (int r = 0; r < 4; ++r)
        tileL[wr * 64 + mi * 16 + g * 4 + r][col] = f2bf(acc[mi][ni][r] + bb);
    }
  __syncthreads();

  int s0 = bm * 128;
  if (bn < 32) {
    // Q: RoPE + scale, write [h][s][128]
    int hq = bn;
    int r = tid >> 1, u = tid & 1;
    int s = s0 + r;
    int ps = pos[s];
    const float* cb = cosT + (size_t)ps * 128;
    const float* sb = sinT + (size_t)ps * 128;
    u16* dst = Q + ((size_t)hq * S_LEN + s) * HD;
    const float qs = 0.08838834764831845f;  // 1/sqrt(128)
#pragma unroll
    for (int c8 = 0; c8 < 4; ++c8) {
      int d0 = u * 32 + c8 * 8;
      u16x8 lo, hi;
#pragma unroll
      for (int j = 0; j < 8; ++j) {
        int d = d0 + j;
        float x0 = bf2f(tileL[r][d]);
        float x1 = bf2f(tileL[r][d + 64]);
        lo[j] = f2bf((x0 * cb[d] - x1 * sb[d]) * qs);
        hi[j] = f2bf((x1 * cb[d + 64] + x0 * sb[d + 64]) * qs);
      }
      *(u16x8*)(dst + d0) = lo;
      *(u16x8*)(dst + d0 + 64) = hi;
    }
  } else if (bn < 40) {
    // K: RoPE, write Kf fragment layout: ((kh*64+t2)*8 + d/16)*512 + ((s&31)+32*((d>>3)&1))*8 + (d&7)
    int kh = bn - 32;
    int r = tid >> 1, u = tid & 1;
    int s = s0 + r;
    int ps = pos[s];
    const float* cb = cosT + (size_t)ps * 128;
    const float* sb = sinT + (size_t)ps * 128;
    int t2 = s >> 5, cr = s & 31;
#pragma unroll
    for (int c8 = 0; c8 < 4; ++c8) {
      int d0 = u * 32 + c8 * 8;
      u16x8 lo, hi;
#pragma unroll
      for (int j = 0; j < 8; ++j) {
        int d = d0 + j;
        float x0 = bf2f(tileL[r][d]);
        float x1 = bf2f(tileL[r][d + 64]);
        lo[j] = f2bf(x0 * cb[d] - x1 * sb[d]);
        hi[j] = f2bf(x1 * cb[d + 64] + x0 * sb[d + 64]);
      }
      size_t base_lo = ((size_t)(kh * 64 + t2) * 8 + (d0 >> 4)) * 512 + (size_t)(cr + 32 * ((d0 >> 3) & 1)) * 8;
      *(u16x8*)(Kf + base_lo) = lo;
      int dh = d0 + 64;
      size_t base_hi = ((size_t)(kh * 64 + t2) * 8 + (dh >> 4)) * 512 + (size_t)(cr + 32 * ((dh >> 3) & 1)) * 8;
      *(u16x8*)(Kf + base_hi) = hi;
    }
  } else {
    // V: write Vf fragment chunks: (kh*512 + t*8 + dt*2 + sl)*512 + l*8 + j
    //    elem j = V[t*32 + sl*16 + (l>>5)*8 + j][dt*32 + (l&31)]
    int kh = bn - 40;
#pragma unroll
    for (int i = 0; i < 8; ++i) {
      int c = i * 256 + tid;
      int lv = c & 63, sl = (c >> 6) & 1, dt = (c >> 7) & 3, t2l = c >> 9;
      int h2 = lv >> 5, c2 = lv & 31;
      int rl = t2l * 32 + sl * 16 + h2 * 8;
      int colv = dt * 32 + c2;
      u16x8 o;
#pragma unroll
      for (int j = 0; j < 8; ++j) o[j] = tileL[rl + j][colv];
      size_t addr = ((size_t)(kh * 512 + (bm * 4 + t2l) * 8 + dt * 2 + sl)) * 512 + (size_t)lv * 8;
      *(u16x8*)(Vf + addr) = o;
    }
  }
}

// ---------------- Pipelined GEMM v4 (out-proj): r9-verified structure ----------------
template <int BM, int BN, int MINW, typename TOUT>
__global__ __launch_bounds__(256, MINW) void gemm4_k(const u16* __restrict__ A, const u16* __restrict__ Bt,
                                                     const float* __restrict__ bias, TOUT* __restrict__ C,
                                                     int M, int N, int K) {
  constexpr int WM = BM / 2, WN = BN / 2;
  constexpr int MRA = WM / 16, MRB = WN / 16;
  constexpr int NA = BM / 64, NB = BN / 64;
  constexpr int NL = NA + NB;
  __shared__ __align__(16) u16 SA[3 * BM * 32];
  __shared__ __align__(16) u16 SB[3 * BN * 32];

  int tid = threadIdx.x;
  int w = tid >> 6, l = tid & 63;
  int cl = l & 15, g = l >> 4;
  int wr = w >> 1, wc = w & 1;

  int cpx = gridDim.x >> 3;
  int wg = (blockIdx.x & 7) * cpx + (blockIdx.x >> 3);
  int nbm = M / BM;
  int bm = wg % nbm, bn = wg / nbm;

  const u16* Ag = A + (size_t)(bm * BM) * K;
  const u16* Bg = Bt + (size_t)(bn * BN) * K;
  int srow = w * 16 + (l >> 2);
  int csrc = ((l & 3) ^ ((l >> 3) & 3)) * 8;
  int rdc = (g ^ ((cl >> 1) & 3)) << 3;

  f32x4 acc[MRA][MRB] = {};
  int NT = K >> 5;

  auto stage = [&](int slot, int tt, int h) {
    if (h < NA) {
      gload16(Ag + (size_t)(h * 64 + srow) * K + tt * 32 + csrc,
              (void*)(SA + slot * (BM * 32) + (h * 64 + w * 16) * 32));
    } else {
      int hb = h - NA;
      gload16(Bg + (size_t)(hb * 64 + srow) * K + tt * 32 + csrc,
              (void*)(SB + slot * (BN * 32) + (hb * 64 + w * 16) * 32));
    }
  };

#pragma unroll
  for (int h = 0; h < NL; ++h) stage(0, 0, h);
#pragma unroll
  for (int h = 0; h < NL; ++h) stage(1, 1, h);

  for (int t = 0; t < NT; ++t) {
    if constexpr (NL == 5) asm volatile("s_waitcnt vmcnt(5)" ::: "memory");
    else if constexpr (NL == 4) asm volatile("s_waitcnt vmcnt(4)" ::: "memory");
    else asm volatile("s_waitcnt vmcnt(3)" ::: "memory");
    __builtin_amdgcn_s_barrier();
    asm volatile("" ::: "memory");

    int slot = t % 3, ss = (t + 2) % 3;
    int ts = t + 2; if (ts >= NT) ts -= NT;
#pragma unroll
    for (int h = 0; h < NL; ++h) stage(ss, ts, h);

    const u16* sa = SA + slot * (BM * 32);
    const u16* sb = SB + slot * (BN * 32);
    bf16x8 af[MRA], bf[MRB];
#pragma unroll
    for (int mi = 0; mi < MRA; ++mi)
      af[mi] = *(const bf16x8*)(sa + (wr * WM + mi * 16 + cl) * 32 + rdc);
#pragma unroll
    for (int ni = 0; ni < MRB; ++ni)
      bf[ni] = *(const bf16x8*)(sb + (wc * WN + ni * 16 + cl) * 32 + rdc);
    __builtin_amdgcn_s_setprio(1);
#pragma unroll
    for (int mi = 0; mi < MRA; ++mi)
#pragma unroll
      for (int ni = 0; ni < MRB; ++ni)
        acc[mi][ni] = __builtin_amdgcn_mfma_f32_16x16x32_bf16(af[mi], bf[ni], acc[mi][ni], 0, 0, 0);
    __builtin_amdgcn_s_setprio(0);
  }

  asm volatile("s_waitcnt vmcnt(0)" ::: "memory");

#pragma unroll
  for (int mi = 0; mi < MRA; ++mi) {
    int row0 = bm * BM + wr * WM + mi * 16 + g * 4;
#pragma unroll
    for (int ni = 0; ni < MRB; ++ni) {
      int col = bn * BN + wc * WN + ni * 16 + cl;
      float bb = bias[col];
      f32x4 a = acc[mi][ni];
#pragma unroll
      for (int r = 0; r < 4; ++r) {
        float v = a[r] + bb;
        if constexpr (sizeof(TOUT) == 2) C[(size_t)(row0 + r) * N + col] = f2bf(v);
        else C[(size_t)(row0 + r) * N + col] = v;
      }
    }
  }
}

// ---------------- flash attention (r11-best) + Wo^T transpose piggyback ----------------
// blocks [0,512): attn (swapped-QK^T 32x32, in-register softmax, K dbuf, qb remap);
// blocks [512,4608): Wo^T transpose (overlaps attn's load-imbalanced tail).
__global__ __launch_bounds__(256, 2) void attnwot_k(const u16* __restrict__ Q, const u16* __restrict__ Kf,
                                                    const u16* __restrict__ Vf, u16* __restrict__ O,
                                                    const float* __restrict__ Wo, u16* __restrict__ WT) {
  __shared__ __align__(16) char smem[17408];
  if (blockIdx.x >= 512) {
    int tt = blockIdx.x - 512;
    transp_f32(Wo, 4096, WT, 4096, tt & 63, tt >> 6, smem);
    return;
  }
  int l = threadIdx.x & 63, w = threadIdx.x >> 6;
  int col = l & 31, hi = l >> 5;
  int bid = blockIdx.x;
  int kh = bid & 7;
  int head = (bid >> 3) & 3;
  int qbp = bid >> 5;
  int qb = (qbp & 1) ? (15 - (qbp >> 1)) : (qbp >> 1);
  int h = kh * 4 + head;
  int q0 = qb * 128 + w * 32;

  bf16x8 qf[8];
  const u16* qbase = Q + ((size_t)h * S_LEN + q0 + col) * HD + hi * 8;
#pragma unroll
  for (int ks = 0; ks < 8; ++ks) qf[ks] = *(const bf16x8*)(qbase + ks * 16);

  f32x16 ot[4];
#pragma unroll
  for (int dt = 0; dt < 4; ++dt)
#pragma unroll
    for (int r = 0; r < 16; ++r) ot[dt][r] = 0.f;
  float m_r = -3.0e38f, l_r = 0.f;

  const u16* kf0 = Kf + (size_t)kh * 64 * 4096 + (size_t)l * 8;
  const u16* vf0 = Vf + (size_t)kh * 512 * 512 + (size_t)l * 8;

  int jstart = q0 >= WIN ? q0 - WIN : 0;
  bf16x8 kfr[8];
  {
    const u16* kb = kf0 + (size_t)(jstart >> 5) * 4096;
#pragma unroll
    for (int ks = 0; ks < 8; ++ks) kfr[ks] = *(const bf16x8*)(kb + ks * 512);
  }

  for (int j0 = jstart; j0 <= q0; j0 += 32) {
    int t = j0 >> 5;
    f32x16 sA = {}, sB = {};
#pragma unroll
    for (int ks = 0; ks < 4; ++ks)
      sA = __builtin_amdgcn_mfma_f32_32x32x16_bf16(kfr[ks], qf[ks], sA, 0, 0, 0);
#pragma unroll
    for (int ks = 4; ks < 8; ++ks)
      sB = __builtin_amdgcn_mfma_f32_32x32x16_bf16(kfr[ks], qf[ks], sB, 0, 0, 0);
    int tn = (j0 + 32 <= q0) ? (t + 1) : t;
    const u16* kbn = kf0 + (size_t)tn * 4096;
    bf16x8 kfn[8];
#pragma unroll
    for (int ks = 0; ks < 8; ++ks) kfn[ks] = *(const bf16x8*)(kbn + ks * 512);
    const u16* vb = vf0 + (size_t)t * 4096;
    bf16x8 vfr[8];
#pragma unroll
    for (int c = 0; c < 8; ++c) vfr[c] = *(const bf16x8*)(vb + c * 512);

    f32x16 s = sA + sB;

    if (j0 + 31 > q0 || j0 < q0 - 992) {
      int q = q0 + col;
#pragma unroll
      for (int r = 0; r < 16; ++r) {
        int kv = j0 + (r & 3) + 8 * (r >> 2) + 4 * hi;
        if (kv > q || kv <= q - WIN) s[r] = -3.0e38f;
      }
    }
    float vm = fmaxf(fmaxf(fmaxf(s[0], s[1]), fmaxf(s[2], s[3])),
                     fmaxf(fmaxf(s[4], s[5]), fmaxf(s[6], s[7])));
    vm = fmaxf(vm, fmaxf(fmaxf(fmaxf(s[8], s[9]), fmaxf(s[10], s[11])),
                         fmaxf(fmaxf(s[12], s[13]), fmaxf(s[14], s[15]))));
    vm = fmaxf(vm, __shfl_xor(vm, 32));
    float mnew = fmaxf(m_r, vm);
    float sc = __expf(m_r - mnew);
    m_r = mnew;
    float rs = 0.f;
#pragma unroll
    for (int r = 0; r < 16; ++r) {
      float pv = __expf(s[r] - mnew);
      s[r] = pv;
      rs += pv;
    }
    rs += __shfl_xor(rs, 32);
    l_r = l_r * sc + rs;
#pragma unroll
    for (int dt = 0; dt < 4; ++dt)
#pragma unroll
      for (int r = 0; r < 16; ++r) ot[dt][r] *= sc;

    bf16x8 pb[2];
#pragma unroll
    for (int sl = 0; sl < 2; ++sl) {
      int b = sl * 8;
      unsigned int a0 = cvtpk_bf16(s[b + 0], s[b + 1]);
      unsigned int c0 = cvtpk_bf16(s[b + 4], s[b + 5]);
      asm("v_permlane32_swap_b32 %0, %1" : "+v"(a0), "+v"(c0));
      unsigned int a1 = cvtpk_bf16(s[b + 2], s[b + 3]);
      unsigned int c1 = cvtpk_bf16(s[b + 6], s[b + 7]);
      asm("v_permlane32_swap_b32 %0, %1" : "+v"(a1), "+v"(c1));
      u32x4 pv = {a0, a1, c0, c1};
      pb[sl] = __builtin_bit_cast(bf16x8, pv);
    }
#pragma unroll
    for (int dt = 0; dt < 4; ++dt) {
      ot[dt] = __builtin_amdgcn_mfma_f32_32x32x16_bf16(vfr[dt * 2 + 0], pb[0], ot[dt], 0, 0, 0);
      ot[dt] = __builtin_amdgcn_mfma_f32_32x32x16_bf16(vfr[dt * 2 + 1], pb[1], ot[dt], 0, 0, 0);
    }
#pragma unroll
    for (int ks = 0; ks < 8; ++ks) kfr[ks] = kfn[ks];
  }

  float inv = 1.0f / l_r;
#pragma unroll
  for (int dt = 0; dt < 4; ++dt) {
#pragma unroll
    for (int g2 = 0; g2 < 4; ++g2) {
      u16x4 o;
#pragma unroll
      for (int i = 0; i < 4; ++i) o[i] = f2bf(ot[dt][g2 * 4 + i] * inv);
      *(u16x4*)(O + (size_t)(q0 + col) * HIDDEN + h * HD + dt * 32 + g2 * 8 + hi * 4) = o;
    }
  }
}

extern "C" void kernel_launch(void* const* d_in, const int* in_sizes, int n_in,
                              void* d_out, int out_size, void* d_ws, size_t ws_size,
                              hipStream_t stream) {
  const float* X = (const float*)d_in[0];
  const int* pos = (const int*)d_in[2];
  const float* cosT = (const float*)d_in[3];
  const float* sinT = (const float*)d_in[4];
  const float* Wq = (const float*)d_in[5];
  const float* bq = (const float*)d_in[6];
  const float* Wk = (const float*)d_in[7];
  const float* bk = (const float*)d_in[8];
  const float* Wv = (const float*)d_in[9];
  const float* bv = (const float*)d_in[10];
  const float* Wo = (const float*)d_in[11];
  const float* bo = (const float*)d_in[12];
  float* out = (float*)d_out;

  const size_t MB = 1ull << 20;
  char* ws = (char*)d_ws;
  u16* WT = (u16*)ws;                     // 48MB: Wqkv^T bf16; Wo^T overwrites after QKV GEMM
  u16* Xb = (u16*)(ws + 48 * MB);         // 16MB: X bf16 (dead after QKV GEMM); attnO reuses
  u16* attnO = Xb;
  u16* Qs = (u16*)(ws + 64 * MB);         // 16MB: Q [32][2048][128] (old QKVr region)
  u16* Kfr = (u16*)(ws + 88 * MB);        // 4MB: K fragment-packed
  u16* Vfr = (u16*)(ws + 92 * MB);        // 4MB: V fragment-packed
  float* bqkv = (float*)(ws + 96 * MB);   // 24KB

  // prep: conv + Wq/Wk/Wv transposes + bias concat
  prep_k<<<10264, 256, 0, stream>>>(X, Wq, Wk, Wv, bq, bk, bv, Xb, WT, bqkv);

  // QKV GEMM + fused RoPE/scatter epilogue: 768 WGs (3/CU), writes Q/Kf/Vf directly
  gemmqkv_k<<<768, 256, 0, stream>>>(Xb, WT, bqkv, pos, cosT, sinT, Qs, Kfr, Vfr, 4096);

  // attn (512 blocks) + Wo^T transpose (4096 blocks, overlaps attn tail)
  attnwot_k<<<4608, 256, 0, stream>>>(Qs, Kfr, Vfr, attnO, Wo, WT);

  // out-proj: 128x128 tiles, 512 WGs
  gemm4_k<128, 128, 3, float><<<512, 256, 0, stream>>>(attnO, WT, bo, out, 2048, 4096, 4096);
}

// Round 16
// 301.101 us; speedup vs baseline: 1.1951x; 1.0664x over previous
//
#include <hip/hip_runtime.h>
#include <stdint.h>

typedef unsigned short u16;
typedef __attribute__((ext_vector_type(4))) float f32x4;
typedef __attribute__((ext_vector_type(16))) float f32x16;
typedef __attribute__((ext_vector_type(8))) __bf16 bf16x8;
typedef __attribute__((ext_vector_type(4))) u16 u16x4;
typedef __attribute__((ext_vector_type(8))) u16 u16x8;
typedef __attribute__((ext_vector_type(4))) unsigned int u32x4;

#define S_LEN 2048
#define HIDDEN 4096
#define NHEAD 32
#define NKVH 8
#define HD 128
#define WIN 1024

__device__ __forceinline__ float bf2f(u16 u) {
  union { unsigned int i; float f; } x; x.i = ((unsigned int)u) << 16; return x.f;
}
__device__ __forceinline__ u16 f2bf(float f) {
  union { float f; unsigned int i; } x; x.f = f;
  unsigned int r = x.i + 0x7FFFu + ((x.i >> 16) & 1u);
  return (u16)(r >> 16);
}

__device__ __forceinline__ void gload16(const void* g, void* l) {
  __builtin_amdgcn_global_load_lds((const __attribute__((address_space(1))) void*)g,
                                   (__attribute__((address_space(3))) void*)l, 16, 0, 0);
}

__device__ __forceinline__ unsigned int cvtpk_bf16(float a, float b) {
  unsigned int w;
  asm("v_cvt_pk_bf16_f32 %0, %1, %2" : "=v"(w) : "v"(a), "v"(b));
  return w;
}

// ---------------- fused fp32->bf16 transpose tile (device fn, shared smem) ----------------
__device__ __forceinline__ void transp_f32(const float* __restrict__ in, int istride,
                                           u16* __restrict__ out, int ostride,
                                           int bx, int by, char* smem) {
  float (*tile)[68] = (float (*)[68])smem;  // 64x68 f32 = 17408 B
  int r0 = bx * 64, c0 = by * 64;
  int t = threadIdx.x;
  int tr = t >> 4;
  int tc = (t & 15) * 4;
#pragma unroll
  for (int i = 0; i < 4; ++i) {
    int r = i * 16 + tr;
    *(f32x4*)&tile[r][tc] = *(const f32x4*)(in + (size_t)(r0 + r) * istride + c0 + tc);
  }
  __syncthreads();
#pragma unroll
  for (int i = 0; i < 4; ++i) {
    int rr = i * 16 + tr;
    u16x4 o;
#pragma unroll
    for (int j = 0; j < 4; ++j) o[j] = f2bf(tile[tc + j][rr]);
    *(u16x4*)(out + (size_t)(c0 + rr) * ostride + r0 + tc) = o;
  }
}

// ---------------- prep: X conv + Wq/Wk/Wv transpose + bias concat (1 launch) ----------------
__global__ __launch_bounds__(256) void prep_k(const float* __restrict__ X,
                                              const float* __restrict__ Wq, const float* __restrict__ Wk,
                                              const float* __restrict__ Wv,
                                              const float* __restrict__ bq, const float* __restrict__ bk,
                                              const float* __restrict__ bv,
                                              u16* __restrict__ Xb, u16* __restrict__ WT,
                                              float* __restrict__ bqkv) {
  __shared__ __align__(16) char smem[17408];
  int bid = blockIdx.x;
  if (bid < 4096) {
    size_t i = ((size_t)bid * 256 + threadIdx.x) * 8;
    f32x4 a = *(const f32x4*)(X + i);
    f32x4 b = *(const f32x4*)(X + i + 4);
    u16x8 o;
    o[0] = f2bf(a[0]); o[1] = f2bf(a[1]); o[2] = f2bf(a[2]); o[3] = f2bf(a[3]);
    o[4] = f2bf(b[0]); o[5] = f2bf(b[1]); o[6] = f2bf(b[2]); o[7] = f2bf(b[3]);
    *(u16x8*)(Xb + i) = o;
  } else if (bid < 8192) {
    int tt = bid - 4096;
    transp_f32(Wq, 4096, WT, 4096, tt & 63, tt >> 6, smem);
  } else if (bid < 9216) {
    int tt = bid - 8192;
    transp_f32(Wk, 1024, WT + (size_t)4096 * 4096, 4096, tt & 63, tt >> 6, smem);
  } else if (bid < 10240) {
    int tt = bid - 9216;
    transp_f32(Wv, 1024, WT + (size_t)5120 * 4096, 4096, tt & 63, tt >> 6, smem);
  } else {
    int i = (bid - 10240) * 256 + threadIdx.x;
    float v = (i < 4096) ? bq[i] : (i < 5120 ? bk[i - 4096] : bv[i - 5120]);
    bqkv[i] = v;
  }
}

// ---------------- QKV GEMM: 256x256 tile (L3-BW fix), r9 loop recipe at 8 waves ----------------
// 512 threads, 8 waves 2Mx4N, wave-out 128x64 (MRA=8, MRB=4, 32 MFMA/barrier). BK=32, ring-3
// (96KB, 1 block/CU), stage whole tile t+2 at top of t, counted vmcnt(4) (never 0 in-loop),
// single barrier/tile. Chunk swizzle (cl>>1)&3 pair (r9-verified, 0 conflicts).
// 256^2 halves staging bytes/FLOP vs 128^2 -> off the measured ~12.5 TB/s L3 ceiling.
// Epilogue: 2 passes of 128 rows through a [128][264] LDS tile (ring is dead), then
// RoPE/scatter with the r15-verified Q/Kf/Vf formulas (2 heads per 256-col tile).
__global__ __launch_bounds__(512, 2) void gemmqkv_k(const u16* __restrict__ A, const u16* __restrict__ Bt,
                                                    const float* __restrict__ bias,
                                                    const int* __restrict__ pos,
                                                    const float* __restrict__ cosT, const float* __restrict__ sinT,
                                                    u16* __restrict__ Q, u16* __restrict__ Kf,
                                                    u16* __restrict__ Vf, int K) {
  __shared__ __align__(16) u16 SM[49152];  // SA: 3x8192, SB: 3x8192 (u16); epilogue tile reuses
  u16* SA = SM;
  u16* SB = SM + 24576;

  int tid = threadIdx.x;
  int w = tid >> 6, l = tid & 63;
  int cl = l & 15, g = l >> 4;
  int wr = w >> 2, wc = w & 3;

  int cpx = gridDim.x >> 3;  // XCD-bijective swizzle (192 % 8 == 0)
  int wg = (blockIdx.x & 7) * cpx + (blockIdx.x >> 3);
  int bm = wg & 7, bn = wg >> 3;  // nbm = 8, bn in [0,24)

  const u16* Ag = A + (size_t)(bm * 256) * K;
  const u16* Bg = Bt + (size_t)(bn * 256) * K;
  int srow = w * 16 + (l >> 2);                  // staging row within a 128-row unit (wave w: rows w*16..+16)
  int csrc = ((l & 3) ^ ((l >> 3) & 3)) * 8;     // inverse-swizzled global k-chunk
  int rdc = (g ^ ((cl >> 1) & 3)) << 3;          // forward swizzle on fragment ds_read

  f32x4 acc[8][4] = {};
  int NT = K >> 5;

  // unit u: 0-1 = A rows u*128..+128; 2-3 = B rows (u-2)*128..+128. 512 thr x 16B = 8KB = unit.
  auto stage = [&](int slot, int tt, int u) {
    if (u < 2) {
      gload16(Ag + (size_t)(u * 128 + srow) * K + tt * 32 + csrc,
              (void*)(SA + slot * 8192 + u * 4096 + w * 512));
    } else {
      int ub = u - 2;
      gload16(Bg + (size_t)(ub * 128 + srow) * K + tt * 32 + csrc,
              (void*)(SB + slot * 8192 + ub * 4096 + w * 512));
    }
  };

#pragma unroll
  for (int u = 0; u < 4; ++u) stage(0, 0, u);
#pragma unroll
  for (int u = 0; u < 4; ++u) stage(1, 1, u);

  for (int t = 0; t < NT; ++t) {
    asm volatile("s_waitcnt vmcnt(4)" ::: "memory");  // tile t done; t+1's 4 stay in flight
    __builtin_amdgcn_s_barrier();
    asm volatile("" ::: "memory");

    int slot = t % 3, ss = (t + 2) % 3;
    int ts = t + 2; if (ts >= NT) ts -= NT;  // dummy wrap keeps vmcnt accounting uniform
#pragma unroll
    for (int u = 0; u < 4; ++u) stage(ss, ts, u);

    const u16* sa = SA + slot * 8192;
    const u16* sb = SB + slot * 8192;
    bf16x8 af[8], bf[4];
#pragma unroll
    for (int mi = 0; mi < 8; ++mi)
      af[mi] = *(const bf16x8*)(sa + (wr * 128 + mi * 16 + cl) * 32 + rdc);
#pragma unroll
    for (int ni = 0; ni < 4; ++ni)
      bf[ni] = *(const bf16x8*)(sb + (wc * 64 + ni * 16 + cl) * 32 + rdc);
    __builtin_amdgcn_s_setprio(1);
#pragma unroll
    for (int mi = 0; mi < 8; ++mi)
#pragma unroll
      for (int ni = 0; ni < 4; ++ni)
        acc[mi][ni] = __builtin_amdgcn_mfma_f32_16x16x32_bf16(af[mi], bf[ni], acc[mi][ni], 0, 0, 0);
    __builtin_amdgcn_s_setprio(0);
  }

  asm volatile("s_waitcnt vmcnt(0)" ::: "memory");  // drain trailing dummy stages
  __syncthreads();

  // ---- epilogue: 2 passes of 128 rows via LDS tile [128][264] (stride 528B = 33*16B, aligned) ----
  u16 (*tileL)[264] = (u16 (*)[264])SM;
  const float qs = 0.08838834764831845f;  // 1/sqrt(128)
#pragma unroll
  for (int hp = 0; hp < 2; ++hp) {
    if (wr == hp) {
#pragma unroll
      for (int mi = 0; mi < 8; ++mi)
#pragma unroll
        for (int ni = 0; ni < 4; ++ni) {
          int col = wc * 64 + ni * 16 + cl;
          float bb = bias[bn * 256 + col];
#pragma unroll
          for (int r = 0; r < 4; ++r)
            tileL[mi * 16 + g * 4 + r][col] = f2bf(acc[mi][ni][r] + bb);
        }
    }
    __syncthreads();

    int s0 = bm * 256 + hp * 128;
    if (bn < 16) {
      // Q: two heads bn*2, bn*2+1; RoPE + scale -> Q[h][s][128]
      int r = tid >> 2, u2 = tid & 3;
      int hl = u2 >> 1, u = u2 & 1;
      int hq = bn * 2 + hl;
      int s = s0 + r;
      int ps = pos[s];
      const float* cb = cosT + (size_t)ps * 128;
      const float* sb = sinT + (size_t)ps * 128;
      u16* dst = Q + ((size_t)hq * S_LEN + s) * HD;
#pragma unroll
      for (int c8 = 0; c8 < 4; ++c8) {
        int d0 = u * 32 + c8 * 8;
        u16x8 xlo = *(const u16x8*)&tileL[r][hl * 128 + d0];
        u16x8 xhi = *(const u16x8*)&tileL[r][hl * 128 + d0 + 64];
        u16x8 lo, hi;
#pragma unroll
        for (int j = 0; j < 8; ++j) {
          int d = d0 + j;
          float x0 = bf2f(xlo[j]);
          float x1 = bf2f(xhi[j]);
          lo[j] = f2bf((x0 * cb[d] - x1 * sb[d]) * qs);
          hi[j] = f2bf((x1 * cb[d + 64] + x0 * sb[d + 64]) * qs);
        }
        *(u16x8*)(dst + d0) = lo;
        *(u16x8*)(dst + d0 + 64) = hi;
      }
    } else if (bn < 20) {
      // K: two heads; RoPE -> Kf layout ((kh*64+t2)*8 + d/16)*512 + ((s&31)+32*((d>>3)&1))*8 + (d&7)
      int r = tid >> 2, u2 = tid & 3;
      int hl = u2 >> 1, u = u2 & 1;
      int kh = (bn - 16) * 2 + hl;
      int s = s0 + r;
      int ps = pos[s];
      const float* cb = cosT + (size_t)ps * 128;
      const float* sb = sinT + (size_t)ps * 128;
      int t2 = s >> 5, cr = s & 31;
#pragma unroll
      for (int c8 = 0; c8 < 4; ++c8) {
        int d0 = u * 32 + c8 * 8;
        u16x8 xlo = *(const u16x8*)&tileL[r][hl * 128 + d0];
        u16x8 xhi = *(const u16x8*)&tileL[r][hl * 128 + d0 + 64];
        u16x8 lo, hi;
#pragma unroll
        for (int j = 0; j < 8; ++j) {
          int d = d0 + j;
          float x0 = bf2f(xlo[j]);
          float x1 = bf2f(xhi[j]);
          lo[j] = f2bf(x0 * cb[d] - x1 * sb[d]);
          hi[j] = f2bf(x1 * cb[d + 64] + x0 * sb[d + 64]);
        }
        size_t base_lo = ((size_t)(kh * 64 + t2) * 8 + (d0 >> 4)) * 512 + (size_t)(cr + 32 * ((d0 >> 3) & 1)) * 8;
        *(u16x8*)(Kf + base_lo) = lo;
        int dh = d0 + 64;
        size_t base_hi = ((size_t)(kh * 64 + t2) * 8 + (dh >> 4)) * 512 + (size_t)(cr + 32 * ((dh >> 3) & 1)) * 8;
        *(u16x8*)(Kf + base_hi) = hi;
      }
    } else {
      // V: two heads -> Vf chunks (kh*512 + t*8 + dt*2 + sl)*512 + lv*8,
      //    elem j = V[tloc*32 + sl*16 + (lv>>5)*8 + j][dt*32 + (lv&31)]
#pragma unroll
      for (int i = 0; i < 8; ++i) {
        int c = i * 512 + tid;
        int lv = c & 63, sl = (c >> 6) & 1, dt = (c >> 7) & 3;
        int t_local = (c >> 9) & 3, hl = c >> 11;
        int kh = (bn - 20) * 2 + hl;
        int rl = t_local * 32 + sl * 16 + (lv >> 5) * 8;
        int colv = hl * 128 + dt * 32 + (lv & 31);
        u16x8 o;
#pragma unroll
        for (int j = 0; j < 8; ++j) o[j] = tileL[rl + j][colv];
        int tglob = bm * 8 + hp * 4 + t_local;
        size_t addr = ((size_t)(kh * 512 + tglob * 8 + dt * 2 + sl)) * 512 + (size_t)lv * 8;
        *(u16x8*)(Vf + addr) = o;
      }
    }
    __syncthreads();
  }
}

// ---------------- Pipelined GEMM v4 (out-proj): r9-verified structure ----------------
template <int BM, int BN, int MINW, typename TOUT>
__global__ __launch_bounds__(256, MINW) void gemm4_k(const u16* __restrict__ A, const u16* __restrict__ Bt,
                                                     const float* __restrict__ bias, TOUT* __restrict__ C,
                                                     int M, int N, int K) {
  constexpr int WM = BM / 2, WN = BN / 2;
  constexpr int MRA = WM / 16, MRB = WN / 16;
  constexpr int NA = BM / 64, NB = BN / 64;
  constexpr int NL = NA + NB;
  __shared__ __align__(16) u16 SA[3 * BM * 32];
  __shared__ __align__(16) u16 SB[3 * BN * 32];

  int tid = threadIdx.x;
  int w = tid >> 6, l = tid & 63;
  int cl = l & 15, g = l >> 4;
  int wr = w >> 1, wc = w & 1;

  int cpx = gridDim.x >> 3;
  int wg = (blockIdx.x & 7) * cpx + (blockIdx.x >> 3);
  int nbm = M / BM;
  int bm = wg % nbm, bn = wg / nbm;

  const u16* Ag = A + (size_t)(bm * BM) * K;
  const u16* Bg = Bt + (size_t)(bn * BN) * K;
  int srow = w * 16 + (l >> 2);
  int csrc = ((l & 3) ^ ((l >> 3) & 3)) * 8;
  int rdc = (g ^ ((cl >> 1) & 3)) << 3;

  f32x4 acc[MRA][MRB] = {};
  int NT = K >> 5;

  auto stage = [&](int slot, int tt, int h) {
    if (h < NA) {
      gload16(Ag + (size_t)(h * 64 + srow) * K + tt * 32 + csrc,
              (void*)(SA + slot * (BM * 32) + (h * 64 + w * 16) * 32));
    } else {
      int hb = h - NA;
      gload16(Bg + (size_t)(hb * 64 + srow) * K + tt * 32 + csrc,
              (void*)(SB + slot * (BN * 32) + (hb * 64 + w * 16) * 32));
    }
  };

#pragma unroll
  for (int h = 0; h < NL; ++h) stage(0, 0, h);
#pragma unroll
  for (int h = 0; h < NL; ++h) stage(1, 1, h);

  for (int t = 0; t < NT; ++t) {
    if constexpr (NL == 5) asm volatile("s_waitcnt vmcnt(5)" ::: "memory");
    else if constexpr (NL == 4) asm volatile("s_waitcnt vmcnt(4)" ::: "memory");
    else asm volatile("s_waitcnt vmcnt(3)" ::: "memory");
    __builtin_amdgcn_s_barrier();
    asm volatile("" ::: "memory");

    int slot = t % 3, ss = (t + 2) % 3;
    int ts = t + 2; if (ts >= NT) ts -= NT;
#pragma unroll
    for (int h = 0; h < NL; ++h) stage(ss, ts, h);

    const u16* sa = SA + slot * (BM * 32);
    const u16* sb = SB + slot * (BN * 32);
    bf16x8 af[MRA], bf[MRB];
#pragma unroll
    for (int mi = 0; mi < MRA; ++mi)
      af[mi] = *(const bf16x8*)(sa + (wr * WM + mi * 16 + cl) * 32 + rdc);
#pragma unroll
    for (int ni = 0; ni < MRB; ++ni)
      bf[ni] = *(const bf16x8*)(sb + (wc * WN + ni * 16 + cl) * 32 + rdc);
    __builtin_amdgcn_s_setprio(1);
#pragma unroll
    for (int mi = 0; mi < MRA; ++mi)
#pragma unroll
      for (int ni = 0; ni < MRB; ++ni)
        acc[mi][ni] = __builtin_amdgcn_mfma_f32_16x16x32_bf16(af[mi], bf[ni], acc[mi][ni], 0, 0, 0);
    __builtin_amdgcn_s_setprio(0);
  }

  asm volatile("s_waitcnt vmcnt(0)" ::: "memory");

#pragma unroll
  for (int mi = 0; mi < MRA; ++mi) {
    int row0 = bm * BM + wr * WM + mi * 16 + g * 4;
#pragma unroll
    for (int ni = 0; ni < MRB; ++ni) {
      int col = bn * BN + wc * WN + ni * 16 + cl;
      float bb = bias[col];
      f32x4 a = acc[mi][ni];
#pragma unroll
      for (int r = 0; r < 4; ++r) {
        float v = a[r] + bb;
        if constexpr (sizeof(TOUT) == 2) C[(size_t)(row0 + r) * N + col] = f2bf(v);
        else C[(size_t)(row0 + r) * N + col] = v;
      }
    }
  }
}

// ---------------- flash attention (r11-best) + Wo^T transpose piggyback ----------------
__global__ __launch_bounds__(256, 2) void attnwot_k(const u16* __restrict__ Q, const u16* __restrict__ Kf,
                                                    const u16* __restrict__ Vf, u16* __restrict__ O,
                                                    const float* __restrict__ Wo, u16* __restrict__ WT) {
  __shared__ __align__(16) char smem[17408];
  if (blockIdx.x >= 512) {
    int tt = blockIdx.x - 512;
    transp_f32(Wo, 4096, WT, 4096, tt & 63, tt >> 6, smem);
    return;
  }
  int l = threadIdx.x & 63, w = threadIdx.x >> 6;
  int col = l & 31, hi = l >> 5;
  int bid = blockIdx.x;
  int kh = bid & 7;
  int head = (bid >> 3) & 3;
  int qbp = bid >> 5;
  int qb = (qbp & 1) ? (15 - (qbp >> 1)) : (qbp >> 1);
  int h = kh * 4 + head;
  int q0 = qb * 128 + w * 32;

  bf16x8 qf[8];
  const u16* qbase = Q + ((size_t)h * S_LEN + q0 + col) * HD + hi * 8;
#pragma unroll
  for (int ks = 0; ks < 8; ++ks) qf[ks] = *(const bf16x8*)(qbase + ks * 16);

  f32x16 ot[4];
#pragma unroll
  for (int dt = 0; dt < 4; ++dt)
#pragma unroll
    for (int r = 0; r < 16; ++r) ot[dt][r] = 0.f;
  float m_r = -3.0e38f, l_r = 0.f;

  const u16* kf0 = Kf + (size_t)kh * 64 * 4096 + (size_t)l * 8;
  const u16* vf0 = Vf + (size_t)kh * 512 * 512 + (size_t)l * 8;

  int jstart = q0 >= WIN ? q0 - WIN : 0;
  bf16x8 kfr[8];
  {
    const u16* kb = kf0 + (size_t)(jstart >> 5) * 4096;
#pragma unroll
    for (int ks = 0; ks < 8; ++ks) kfr[ks] = *(const bf16x8*)(kb + ks * 512);
  }

  for (int j0 = jstart; j0 <= q0; j0 += 32) {
    int t = j0 >> 5;
    f32x16 sA = {}, sB = {};
#pragma unroll
    for (int ks = 0; ks < 4; ++ks)
      sA = __builtin_amdgcn_mfma_f32_32x32x16_bf16(kfr[ks], qf[ks], sA, 0, 0, 0);
#pragma unroll
    for (int ks = 4; ks < 8; ++ks)
      sB = __builtin_amdgcn_mfma_f32_32x32x16_bf16(kfr[ks], qf[ks], sB, 0, 0, 0);
    int tn = (j0 + 32 <= q0) ? (t + 1) : t;
    const u16* kbn = kf0 + (size_t)tn * 4096;
    bf16x8 kfn[8];
#pragma unroll
    for (int ks = 0; ks < 8; ++ks) kfn[ks] = *(const bf16x8*)(kbn + ks * 512);
    const u16* vb = vf0 + (size_t)t * 4096;
    bf16x8 vfr[8];
#pragma unroll
    for (int c = 0; c < 8; ++c) vfr[c] = *(const bf16x8*)(vb + c * 512);

    f32x16 s = sA + sB;

    if (j0 + 31 > q0 || j0 < q0 - 992) {
      int q = q0 + col;
#pragma unroll
      for (int r = 0; r < 16; ++r) {
        int kv = j0 + (r & 3) + 8 * (r >> 2) + 4 * hi;
        if (kv > q || kv <= q - WIN) s[r] = -3.0e38f;
      }
    }
    float vm = fmaxf(fmaxf(fmaxf(s[0], s[1]), fmaxf(s[2], s[3])),
                     fmaxf(fmaxf(s[4], s[5]), fmaxf(s[6], s[7])));
    vm = fmaxf(vm, fmaxf(fmaxf(fmaxf(s[8], s[9]), fmaxf(s[10], s[11])),
                         fmaxf(fmaxf(s[12], s[13]), fmaxf(s[14], s[15]))));
    vm = fmaxf(vm, __shfl_xor(vm, 32));
    float mnew = fmaxf(m_r, vm);
    float sc = __expf(m_r - mnew);
    m_r = mnew;
    float rs = 0.f;
#pragma unroll
    for (int r = 0; r < 16; ++r) {
      float pv = __expf(s[r] - mnew);
      s[r] = pv;
      rs += pv;
    }
    rs += __shfl_xor(rs, 32);
    l_r = l_r * sc + rs;
#pragma unroll
    for (int dt = 0; dt < 4; ++dt)
#pragma unroll
      for (int r = 0; r < 16; ++r) ot[dt][r] *= sc;

    bf16x8 pb[2];
#pragma unroll
    for (int sl = 0; sl < 2; ++sl) {
      int b = sl * 8;
      unsigned int a0 = cvtpk_bf16(s[b + 0], s[b + 1]);
      unsigned int c0 = cvtpk_bf16(s[b + 4], s[b + 5]);
      asm("v_permlane32_swap_b32 %0, %1" : "+v"(a0), "+v"(c0));
      unsigned int a1 = cvtpk_bf16(s[b + 2], s[b + 3]);
      unsigned int c1 = cvtpk_bf16(s[b + 6], s[b + 7]);
      asm("v_permlane32_swap_b32 %0, %1" : "+v"(a1), "+v"(c1));
      u32x4 pv = {a0, a1, c0, c1};
      pb[sl] = __builtin_bit_cast(bf16x8, pv);
    }
#pragma unroll
    for (int dt = 0; dt < 4; ++dt) {
      ot[dt] = __builtin_amdgcn_mfma_f32_32x32x16_bf16(vfr[dt * 2 + 0], pb[0], ot[dt], 0, 0, 0);
      ot[dt] = __builtin_amdgcn_mfma_f32_32x32x16_bf16(vfr[dt * 2 + 1], pb[1], ot[dt], 0, 0, 0);
    }
#pragma unroll
    for (int ks = 0; ks < 8; ++ks) kfr[ks] = kfn[ks];
  }

  float inv = 1.0f / l_r;
#pragma unroll
  for (int dt = 0; dt < 4; ++dt) {
#pragma unroll
    for (int g2 = 0; g2 < 4; ++g2) {
      u16x4 o;
#pragma unroll
      for (int i = 0; i < 4; ++i) o[i] = f2bf(ot[dt][g2 * 4 + i] * inv);
      *(u16x4*)(O + (size_t)(q0 + col) * HIDDEN + h * HD + dt * 32 + g2 * 8 + hi * 4) = o;
    }
  }
}

extern "C" void kernel_launch(void* const* d_in, const int* in_sizes, int n_in,
                              void* d_out, int out_size, void* d_ws, size_t ws_size,
                              hipStream_t stream) {
  const float* X = (const float*)d_in[0];
  const int* pos = (const int*)d_in[2];
  const float* cosT = (const float*)d_in[3];
  const float* sinT = (const float*)d_in[4];
  const float* Wq = (const float*)d_in[5];
  const float* bq = (const float*)d_in[6];
  const float* Wk = (const float*)d_in[7];
  const float* bk = (const float*)d_in[8];
  const float* Wv = (const float*)d_in[9];
  const float* bv = (const float*)d_in[10];
  const float* Wo = (const float*)d_in[11];
  const float* bo = (const float*)d_in[12];
  float* out = (float*)d_out;

  const size_t MB = 1ull << 20;
  char* ws = (char*)d_ws;
  u16* WT = (u16*)ws;                     // 48MB: Wqkv^T bf16; Wo^T overwrites after QKV GEMM
  u16* Xb = (u16*)(ws + 48 * MB);         // 16MB: X bf16 (dead after QKV GEMM); attnO reuses
  u16* attnO = Xb;
  u16* Qs = (u16*)(ws + 64 * MB);         // 16MB: Q [32][2048][128]
  u16* Kfr = (u16*)(ws + 88 * MB);        // 4MB: K fragment-packed
  u16* Vfr = (u16*)(ws + 92 * MB);        // 4MB: V fragment-packed
  float* bqkv = (float*)(ws + 96 * MB);   // 24KB

  // prep: conv + Wq/Wk/Wv transposes + bias concat
  prep_k<<<10264, 256, 0, stream>>>(X, Wq, Wk, Wv, bq, bk, bv, Xb, WT, bqkv);

  // QKV GEMM (256x256 tiles, 192 WGs) + fused RoPE/scatter epilogue
  gemmqkv_k<<<192, 512, 0, stream>>>(Xb, WT, bqkv, pos, cosT, sinT, Qs, Kfr, Vfr, 4096);

  // attn (512 blocks) + Wo^T transpose (4096 blocks, overlaps attn tail)
  attnwot_k<<<4608, 256, 0, stream>>>(Qs, Kfr, Vfr, attnO, Wo, WT);

  // out-proj: 128x128 tiles, 512 WGs
  gemm4_k<128, 128, 3, float><<<512, 256, 0, stream>>>(attnO, WT, bo, out, 2048, 4096, 4096);
}

// Round 17
// 285.792 us; speedup vs baseline: 1.2592x; 1.0536x over previous
//
#include <hip/hip_runtime.h>
#include <stdint.h>

typedef unsigned short u16;
typedef __attribute__((ext_vector_type(4))) float f32x4;
typedef __attribute__((ext_vector_type(16))) float f32x16;
typedef __attribute__((ext_vector_type(8))) __bf16 bf16x8;
typedef __attribute__((ext_vector_type(4))) u16 u16x4;
typedef __attribute__((ext_vector_type(8))) u16 u16x8;
typedef __attribute__((ext_vector_type(4))) unsigned int u32x4;

#define S_LEN 2048
#define HIDDEN 4096
#define NHEAD 32
#define NKVH 8
#define HD 128
#define WIN 1024

__device__ __forceinline__ float bf2f(u16 u) {
  union { unsigned int i; float f; } x; x.i = ((unsigned int)u) << 16; return x.f;
}
__device__ __forceinline__ u16 f2bf(float f) {
  union { float f; unsigned int i; } x; x.f = f;
  unsigned int r = x.i + 0x7FFFu + ((x.i >> 16) & 1u);
  return (u16)(r >> 16);
}

__device__ __forceinline__ void gload16(const void* g, void* l) {
  __builtin_amdgcn_global_load_lds((const __attribute__((address_space(1))) void*)g,
                                   (__attribute__((address_space(3))) void*)l, 16, 0, 0);
}

__device__ __forceinline__ unsigned int cvtpk_bf16(float a, float b) {
  unsigned int w;
  asm("v_cvt_pk_bf16_f32 %0, %1, %2" : "=v"(w) : "v"(a), "v"(b));
  return w;
}

// ---------------- fused fp32->bf16 transpose tile (device fn, shared smem) ----------------
__device__ __forceinline__ void transp_f32(const float* __restrict__ in, int istride,
                                           u16* __restrict__ out, int ostride,
                                           int bx, int by, char* smem) {
  float (*tile)[68] = (float (*)[68])smem;  // 64x68 f32 = 17408 B
  int r0 = bx * 64, c0 = by * 64;
  int t = threadIdx.x;
  int tr = t >> 4;
  int tc = (t & 15) * 4;
#pragma unroll
  for (int i = 0; i < 4; ++i) {
    int r = i * 16 + tr;
    *(f32x4*)&tile[r][tc] = *(const f32x4*)(in + (size_t)(r0 + r) * istride + c0 + tc);
  }
  __syncthreads();
#pragma unroll
  for (int i = 0; i < 4; ++i) {
    int rr = i * 16 + tr;
    u16x4 o;
#pragma unroll
    for (int j = 0; j < 4; ++j) o[j] = f2bf(tile[tc + j][rr]);
    *(u16x4*)(out + (size_t)(c0 + rr) * ostride + r0 + tc) = o;
  }
}

// ---------------- prep: X conv + Wq/Wk/Wv transpose + bias concat (1 launch) ----------------
__global__ __launch_bounds__(256) void prep_k(const float* __restrict__ X,
                                              const float* __restrict__ Wq, const float* __restrict__ Wk,
                                              const float* __restrict__ Wv,
                                              const float* __restrict__ bq, const float* __restrict__ bk,
                                              const float* __restrict__ bv,
                                              u16* __restrict__ Xb, u16* __restrict__ WT,
                                              float* __restrict__ bqkv) {
  __shared__ __align__(16) char smem[17408];
  int bid = blockIdx.x;
  if (bid < 4096) {
    size_t i = ((size_t)bid * 256 + threadIdx.x) * 8;
    f32x4 a = *(const f32x4*)(X + i);
    f32x4 b = *(const f32x4*)(X + i + 4);
    u16x8 o;
    o[0] = f2bf(a[0]); o[1] = f2bf(a[1]); o[2] = f2bf(a[2]); o[3] = f2bf(a[3]);
    o[4] = f2bf(b[0]); o[5] = f2bf(b[1]); o[6] = f2bf(b[2]); o[7] = f2bf(b[3]);
    *(u16x8*)(Xb + i) = o;
  } else if (bid < 8192) {
    int tt = bid - 4096;
    transp_f32(Wq, 4096, WT, 4096, tt & 63, tt >> 6, smem);
  } else if (bid < 9216) {
    int tt = bid - 8192;
    transp_f32(Wk, 1024, WT + (size_t)4096 * 4096, 4096, tt & 63, tt >> 6, smem);
  } else if (bid < 10240) {
    int tt = bid - 9216;
    transp_f32(Wv, 1024, WT + (size_t)5120 * 4096, 4096, tt & 63, tt >> 6, smem);
  } else {
    int i = (bid - 10240) * 256 + threadIdx.x;
    float v = (i < 4096) ? bq[i] : (i < 5120 ? bk[i - 4096] : bv[i - 5120]);
    bqkv[i] = v;
  }
}

// ---------------- QKV GEMM: 128x384 tile -> grid 16x16 = 256 WGs (100% CU coverage) ----------------
// r16 loop verbatim at new geometry: 512 threads, 8 waves 2Mx4N, wave-out 64x96 (MRA=4, MRB=6,
// 24 MFMA/barrier). BK=32, ring-3 (96KB), stage whole tile t+2 at top of t, counted vmcnt(4)
// (NL=4 uniform: A 1 unit + B 3 units of 128 rows), single barrier/tile, (cl>>1)&3 swizzle pair.
// Epilogue: 2 passes of 64 rows via [64][392] LDS tile; 3 head-blocks (128 cols each, always
// uniformly Q, K, or V) scattered with the r15/r16-verified Q/Kf/Vf formulas.
__global__ __launch_bounds__(512, 2) void gemmqkv_k(const u16* __restrict__ A, const u16* __restrict__ Bt,
                                                    const float* __restrict__ bias,
                                                    const int* __restrict__ pos,
                                                    const float* __restrict__ cosT, const float* __restrict__ sinT,
                                                    u16* __restrict__ Q, u16* __restrict__ Kf,
                                                    u16* __restrict__ Vf, int K) {
  __shared__ __align__(16) u16 SM[49152];  // SA: 3x4096 u16, SB: 3x12288 u16 (96KB); epilogue reuses
  u16* SA = SM;
  u16* SB = SM + 12288;

  int tid = threadIdx.x;
  int w = tid >> 6, l = tid & 63;
  int cl = l & 15, g = l >> 4;
  int wr = w >> 2, wc = w & 3;

  int cpx = gridDim.x >> 3;  // XCD-bijective swizzle (256 % 8 == 0)
  int wg = (blockIdx.x & 7) * cpx + (blockIdx.x >> 3);
  int bm = wg & 15, bn = wg >> 4;  // nbm = 16, bn in [0,16)

  const u16* Ag = A + (size_t)(bm * 128) * K;
  const u16* Bg = Bt + (size_t)(bn * 384) * K;
  int srow = w * 16 + (l >> 2);                  // staging row within a 128-row unit
  int csrc = ((l & 3) ^ ((l >> 3) & 3)) * 8;     // inverse-swizzled global k-chunk
  int rdc = (g ^ ((cl >> 1) & 3)) << 3;          // forward swizzle on fragment ds_read

  f32x4 acc[4][6] = {};
  int NT = K >> 5;

  // unit 0 = A rows 0..128; units 1-3 = B rows (u-1)*128..+128. 512 thr x 16B = 8KB/unit.
  auto stage = [&](int slot, int tt, int u) {
    if (u == 0) {
      gload16(Ag + (size_t)srow * K + tt * 32 + csrc,
              (void*)(SA + slot * 4096 + w * 512));
    } else {
      int ub = u - 1;
      gload16(Bg + (size_t)(ub * 128 + srow) * K + tt * 32 + csrc,
              (void*)(SB + slot * 12288 + ub * 4096 + w * 512));
    }
  };

#pragma unroll
  for (int u = 0; u < 4; ++u) stage(0, 0, u);
#pragma unroll
  for (int u = 0; u < 4; ++u) stage(1, 1, u);

  for (int t = 0; t < NT; ++t) {
    asm volatile("s_waitcnt vmcnt(4)" ::: "memory");  // tile t done; t+1's 4 stay in flight
    __builtin_amdgcn_s_barrier();
    asm volatile("" ::: "memory");

    int slot = t % 3, ss = (t + 2) % 3;
    int ts = t + 2; if (ts >= NT) ts -= NT;  // dummy wrap keeps vmcnt accounting uniform
#pragma unroll
    for (int u = 0; u < 4; ++u) stage(ss, ts, u);

    const u16* sa = SA + slot * 4096;
    const u16* sb = SB + slot * 12288;
    bf16x8 af[4], bf[6];
#pragma unroll
    for (int mi = 0; mi < 4; ++mi)
      af[mi] = *(const bf16x8*)(sa + (wr * 64 + mi * 16 + cl) * 32 + rdc);
#pragma unroll
    for (int ni = 0; ni < 6; ++ni)
      bf[ni] = *(const bf16x8*)(sb + (wc * 96 + ni * 16 + cl) * 32 + rdc);
    __builtin_amdgcn_s_setprio(1);
#pragma unroll
    for (int mi = 0; mi < 4; ++mi)
#pragma unroll
      for (int ni = 0; ni < 6; ++ni)
        acc[mi][ni] = __builtin_amdgcn_mfma_f32_16x16x32_bf16(af[mi], bf[ni], acc[mi][ni], 0, 0, 0);
    __builtin_amdgcn_s_setprio(0);
  }

  asm volatile("s_waitcnt vmcnt(0)" ::: "memory");  // drain trailing dummy stages
  __syncthreads();

  // ---- epilogue: 2 passes of 64 rows via LDS tile [64][392] (stride 784B = 49*16B) ----
  u16 (*tileL)[392] = (u16 (*)[392])SM;
  const float qs = 0.08838834764831845f;  // 1/sqrt(128)
#pragma unroll
  for (int hp = 0; hp < 2; ++hp) {
    if (wr == hp) {
#pragma unroll
      for (int mi = 0; mi < 4; ++mi)
#pragma unroll
        for (int ni = 0; ni < 6; ++ni) {
          int col = wc * 96 + ni * 16 + cl;
          float bb = bias[bn * 384 + col];
#pragma unroll
          for (int r = 0; r < 4; ++r)
            tileL[mi * 16 + g * 4 + r][col] = f2bf(acc[mi][ni][r] + bb);
        }
    }
    __syncthreads();

    int s0 = bm * 128 + hp * 64;
#pragma unroll
    for (int hl = 0; hl < 3; ++hl) {
      int c0 = bn * 384 + hl * 128;  // 128-aligned global col base
      int hidx = c0 >> 7;            // [0,48): <32 Q, <40 K, else V
      if (hidx < 32) {
        // Q head hidx: RoPE + scale -> Q[h][s][128]
        int r = tid >> 3, u = tid & 7;
        int s = s0 + r;
        int ps = pos[s];
        const float* cb = cosT + (size_t)ps * 128;
        const float* sb = sinT + (size_t)ps * 128;
        u16* dst = Q + ((size_t)hidx * S_LEN + s) * HD;
        int d0 = u * 8;
        u16x8 xlo = *(const u16x8*)&tileL[r][hl * 128 + d0];
        u16x8 xhi = *(const u16x8*)&tileL[r][hl * 128 + d0 + 64];
        u16x8 lo, hi;
#pragma unroll
        for (int j = 0; j < 8; ++j) {
          int d = d0 + j;
          float x0 = bf2f(xlo[j]);
          float x1 = bf2f(xhi[j]);
          lo[j] = f2bf((x0 * cb[d] - x1 * sb[d]) * qs);
          hi[j] = f2bf((x1 * cb[d + 64] + x0 * sb[d + 64]) * qs);
        }
        *(u16x8*)(dst + d0) = lo;
        *(u16x8*)(dst + d0 + 64) = hi;
      } else if (hidx < 40) {
        // K head: RoPE -> Kf layout ((kh*64+t2)*8 + d/16)*512 + ((s&31)+32*((d>>3)&1))*8 + (d&7)
        int kh = hidx - 32;
        int r = tid >> 3, u = tid & 7;
        int s = s0 + r;
        int ps = pos[s];
        const float* cb = cosT + (size_t)ps * 128;
        const float* sb = sinT + (size_t)ps * 128;
        int t2 = s >> 5, cr = s & 31;
        int d0 = u * 8;
        u16x8 xlo = *(const u16x8*)&tileL[r][hl * 128 + d0];
        u16x8 xhi = *(const u16x8*)&tileL[r][hl * 128 + d0 + 64];
        u16x8 lo, hi;
#pragma unroll
        for (int j = 0; j < 8; ++j) {
          int d = d0 + j;
          float x0 = bf2f(xlo[j]);
          float x1 = bf2f(xhi[j]);
          lo[j] = f2bf(x0 * cb[d] - x1 * sb[d]);
          hi[j] = f2bf(x1 * cb[d + 64] + x0 * sb[d + 64]);
        }
        size_t base_lo = ((size_t)(kh * 64 + t2) * 8 + (d0 >> 4)) * 512 + (size_t)(cr + 32 * ((d0 >> 3) & 1)) * 8;
        *(u16x8*)(Kf + base_lo) = lo;
        int dh = d0 + 64;
        size_t base_hi = ((size_t)(kh * 64 + t2) * 8 + (dh >> 4)) * 512 + (size_t)(cr + 32 * ((dh >> 3) & 1)) * 8;
        *(u16x8*)(Kf + base_hi) = hi;
      } else {
        // V head -> Vf chunks (kh*512 + tglob*8 + dt*2 + sl)*512 + lv*8,
        //   elem j = V[t_local*32 + sl*16 + (lv>>5)*8 + j][dt*32 + (lv&31)]
        int kh = hidx - 40;
#pragma unroll
        for (int i = 0; i < 2; ++i) {
          int c = i * 512 + tid;  // [0,1024): 2 t_local x 8 (dt,sl) x 64 lanes
          int lv = c & 63, sl = (c >> 6) & 1, dt = (c >> 7) & 3, t_local = (c >> 9) & 1;
          int rl = t_local * 32 + sl * 16 + (lv >> 5) * 8;
          int colv = hl * 128 + dt * 32 + (lv & 31);
          u16x8 o;
#pragma unroll
          for (int j = 0; j < 8; ++j) o[j] = tileL[rl + j][colv];
          int tglob = bm * 4 + hp * 2 + t_local;
          size_t addr = ((size_t)(kh * 512 + tglob * 8 + dt * 2 + sl)) * 512 + (size_t)lv * 8;
          *(u16x8*)(Vf + addr) = o;
        }
      }
    }
    __syncthreads();
  }
}

// ---------------- Pipelined GEMM v4 (out-proj): r9-verified structure ----------------
template <int BM, int BN, int MINW, typename TOUT>
__global__ __launch_bounds__(256, MINW) void gemm4_k(const u16* __restrict__ A, const u16* __restrict__ Bt,
                                                     const float* __restrict__ bias, TOUT* __restrict__ C,
                                                     int M, int N, int K) {
  constexpr int WM = BM / 2, WN = BN / 2;
  constexpr int MRA = WM / 16, MRB = WN / 16;
  constexpr int NA = BM / 64, NB = BN / 64;
  constexpr int NL = NA + NB;
  __shared__ __align__(16) u16 SA[3 * BM * 32];
  __shared__ __align__(16) u16 SB[3 * BN * 32];

  int tid = threadIdx.x;
  int w = tid >> 6, l = tid & 63;
  int cl = l & 15, g = l >> 4;
  int wr = w >> 1, wc = w & 1;

  int cpx = gridDim.x >> 3;
  int wg = (blockIdx.x & 7) * cpx + (blockIdx.x >> 3);
  int nbm = M / BM;
  int bm = wg % nbm, bn = wg / nbm;

  const u16* Ag = A + (size_t)(bm * BM) * K;
  const u16* Bg = Bt + (size_t)(bn * BN) * K;
  int srow = w * 16 + (l >> 2);
  int csrc = ((l & 3) ^ ((l >> 3) & 3)) * 8;
  int rdc = (g ^ ((cl >> 1) & 3)) << 3;

  f32x4 acc[MRA][MRB] = {};
  int NT = K >> 5;

  auto stage = [&](int slot, int tt, int h) {
    if (h < NA) {
      gload16(Ag + (size_t)(h * 64 + srow) * K + tt * 32 + csrc,
              (void*)(SA + slot * (BM * 32) + (h * 64 + w * 16) * 32));
    } else {
      int hb = h - NA;
      gload16(Bg + (size_t)(hb * 64 + srow) * K + tt * 32 + csrc,
              (void*)(SB + slot * (BN * 32) + (hb * 64 + w * 16) * 32));
    }
  };

#pragma unroll
  for (int h = 0; h < NL; ++h) stage(0, 0, h);
#pragma unroll
  for (int h = 0; h < NL; ++h) stage(1, 1, h);

  for (int t = 0; t < NT; ++t) {
    if constexpr (NL == 5) asm volatile("s_waitcnt vmcnt(5)" ::: "memory");
    else if constexpr (NL == 4) asm volatile("s_waitcnt vmcnt(4)" ::: "memory");
    else asm volatile("s_waitcnt vmcnt(3)" ::: "memory");
    __builtin_amdgcn_s_barrier();
    asm volatile("" ::: "memory");

    int slot = t % 3, ss = (t + 2) % 3;
    int ts = t + 2; if (ts >= NT) ts -= NT;
#pragma unroll
    for (int h = 0; h < NL; ++h) stage(ss, ts, h);

    const u16* sa = SA + slot * (BM * 32);
    const u16* sb = SB + slot * (BN * 32);
    bf16x8 af[MRA], bf[MRB];
#pragma unroll
    for (int mi = 0; mi < MRA; ++mi)
      af[mi] = *(const bf16x8*)(sa + (wr * WM + mi * 16 + cl) * 32 + rdc);
#pragma unroll
    for (int ni = 0; ni < MRB; ++ni)
      bf[ni] = *(const bf16x8*)(sb + (wc * WN + ni * 16 + cl) * 32 + rdc);
    __builtin_amdgcn_s_setprio(1);
#pragma unroll
    for (int mi = 0; mi < MRA; ++mi)
#pragma unroll
      for (int ni = 0; ni < MRB; ++ni)
        acc[mi][ni] = __builtin_amdgcn_mfma_f32_16x16x32_bf16(af[mi], bf[ni], acc[mi][ni], 0, 0, 0);
    __builtin_amdgcn_s_setprio(0);
  }

  asm volatile("s_waitcnt vmcnt(0)" ::: "memory");

#pragma unroll
  for (int mi = 0; mi < MRA; ++mi) {
    int row0 = bm * BM + wr * WM + mi * 16 + g * 4;
#pragma unroll
    for (int ni = 0; ni < MRB; ++ni) {
      int col = bn * BN + wc * WN + ni * 16 + cl;
      float bb = bias[col];
      f32x4 a = acc[mi][ni];
#pragma unroll
      for (int r = 0; r < 4; ++r) {
        float v = a[r] + bb;
        if constexpr (sizeof(TOUT) == 2) C[(size_t)(row0 + r) * N + col] = f2bf(v);
        else C[(size_t)(row0 + r) * N + col] = v;
      }
    }
  }
}

// ---------------- flash attention (r11-best) + Wo^T transpose piggyback ----------------
__global__ __launch_bounds__(256, 2) void attnwot_k(const u16* __restrict__ Q, const u16* __restrict__ Kf,
                                                    const u16* __restrict__ Vf, u16* __restrict__ O,
                                                    const float* __restrict__ Wo, u16* __restrict__ WT) {
  __shared__ __align__(16) char smem[17408];
  if (blockIdx.x >= 512) {
    int tt = blockIdx.x - 512;
    transp_f32(Wo, 4096, WT, 4096, tt & 63, tt >> 6, smem);
    return;
  }
  int l = threadIdx.x & 63, w = threadIdx.x >> 6;
  int col = l & 31, hi = l >> 5;
  int bid = blockIdx.x;
  int kh = bid & 7;
  int head = (bid >> 3) & 3;
  int qbp = bid >> 5;
  int qb = (qbp & 1) ? (15 - (qbp >> 1)) : (qbp >> 1);
  int h = kh * 4 + head;
  int q0 = qb * 128 + w * 32;

  bf16x8 qf[8];
  const u16* qbase = Q + ((size_t)h * S_LEN + q0 + col) * HD + hi * 8;
#pragma unroll
  for (int ks = 0; ks < 8; ++ks) qf[ks] = *(const bf16x8*)(qbase + ks * 16);

  f32x16 ot[4];
#pragma unroll
  for (int dt = 0; dt < 4; ++dt)
#pragma unroll
    for (int r = 0; r < 16; ++r) ot[dt][r] = 0.f;
  float m_r = -3.0e38f, l_r = 0.f;

  const u16* kf0 = Kf + (size_t)kh * 64 * 4096 + (size_t)l * 8;
  const u16* vf0 = Vf + (size_t)kh * 512 * 512 + (size_t)l * 8;

  int jstart = q0 >= WIN ? q0 - WIN : 0;
  bf16x8 kfr[8];
  {
    const u16* kb = kf0 + (size_t)(jstart >> 5) * 4096;
#pragma unroll
    for (int ks = 0; ks < 8; ++ks) kfr[ks] = *(const bf16x8*)(kb + ks * 512);
  }

  for (int j0 = jstart; j0 <= q0; j0 += 32) {
    int t = j0 >> 5;
    f32x16 sA = {}, sB = {};
#pragma unroll
    for (int ks = 0; ks < 4; ++ks)
      sA = __builtin_amdgcn_mfma_f32_32x32x16_bf16(kfr[ks], qf[ks], sA, 0, 0, 0);
#pragma unroll
    for (int ks = 4; ks < 8; ++ks)
      sB = __builtin_amdgcn_mfma_f32_32x32x16_bf16(kfr[ks], qf[ks], sB, 0, 0, 0);
    int tn = (j0 + 32 <= q0) ? (t + 1) : t;
    const u16* kbn = kf0 + (size_t)tn * 4096;
    bf16x8 kfn[8];
#pragma unroll
    for (int ks = 0; ks < 8; ++ks) kfn[ks] = *(const bf16x8*)(kbn + ks * 512);
    const u16* vb = vf0 + (size_t)t * 4096;
    bf16x8 vfr[8];
#pragma unroll
    for (int c = 0; c < 8; ++c) vfr[c] = *(const bf16x8*)(vb + c * 512);

    f32x16 s = sA + sB;

    if (j0 + 31 > q0 || j0 < q0 - 992) {
      int q = q0 + col;
#pragma unroll
      for (int r = 0; r < 16; ++r) {
        int kv = j0 + (r & 3) + 8 * (r >> 2) + 4 * hi;
        if (kv > q || kv <= q - WIN) s[r] = -3.0e38f;
      }
    }
    float vm = fmaxf(fmaxf(fmaxf(s[0], s[1]), fmaxf(s[2], s[3])),
                     fmaxf(fmaxf(s[4], s[5]), fmaxf(s[6], s[7])));
    vm = fmaxf(vm, fmaxf(fmaxf(fmaxf(s[8], s[9]), fmaxf(s[10], s[11])),
                         fmaxf(fmaxf(s[12], s[13]), fmaxf(s[14], s[15]))));
    vm = fmaxf(vm, __shfl_xor(vm, 32));
    float mnew = fmaxf(m_r, vm);
    float sc = __expf(m_r - mnew);
    m_r = mnew;
    float rs = 0.f;
#pragma unroll
    for (int r = 0; r < 16; ++r) {
      float pv = __expf(s[r] - mnew);
      s[r] = pv;
      rs += pv;
    }
    rs += __shfl_xor(rs, 32);
    l_r = l_r * sc + rs;
#pragma unroll
    for (int dt = 0; dt < 4; ++dt)
#pragma unroll
      for (int r = 0; r < 16; ++r) ot[dt][r] *= sc;

    bf16x8 pb[2];
#pragma unroll
    for (int sl = 0; sl < 2; ++sl) {
      int b = sl * 8;
      unsigned int a0 = cvtpk_bf16(s[b + 0], s[b + 1]);
      unsigned int c0 = cvtpk_bf16(s[b + 4], s[b + 5]);
      asm("v_permlane32_swap_b32 %0, %1" : "+v"(a0), "+v"(c0));
      unsigned int a1 = cvtpk_bf16(s[b + 2], s[b + 3]);
      unsigned int c1 = cvtpk_bf16(s[b + 6], s[b + 7]);
      asm("v_permlane32_swap_b32 %0, %1" : "+v"(a1), "+v"(c1));
      u32x4 pv = {a0, a1, c0, c1};
      pb[sl] = __builtin_bit_cast(bf16x8, pv);
    }
#pragma unroll
    for (int dt = 0; dt < 4; ++dt) {
      ot[dt] = __builtin_amdgcn_mfma_f32_32x32x16_bf16(vfr[dt * 2 + 0], pb[0], ot[dt], 0, 0, 0);
      ot[dt] = __builtin_amdgcn_mfma_f32_32x32x16_bf16(vfr[dt * 2 + 1], pb[1], ot[dt], 0, 0, 0);
    }
#pragma unroll
    for (int ks = 0; ks < 8; ++ks) kfr[ks] = kfn[ks];
  }

  float inv = 1.0f / l_r;
#pragma unroll
  for (int dt = 0; dt < 4; ++dt) {
#pragma unroll
    for (int g2 = 0; g2 < 4; ++g2) {
      u16x4 o;
#pragma unroll
      for (int i = 0; i < 4; ++i) o[i] = f2bf(ot[dt][g2 * 4 + i] * inv);
      *(u16x4*)(O + (size_t)(q0 + col) * HIDDEN + h * HD + dt * 32 + g2 * 8 + hi * 4) = o;
    }
  }
}

extern "C" void kernel_launch(void* const* d_in, const int* in_sizes, int n_in,
                              void* d_out, int out_size, void* d_ws, size_t ws_size,
                              hipStream_t stream) {
  const float* X = (const float*)d_in[0];
  const int* pos = (const int*)d_in[2];
  const float* cosT = (const float*)d_in[3];
  const float* sinT = (const float*)d_in[4];
  const float* Wq = (const float*)d_in[5];
  const float* bq = (const float*)d_in[6];
  const float* Wk = (const float*)d_in[7];
  const float* bk = (const float*)d_in[8];
  const float* Wv = (const float*)d_in[9];
  const float* bv = (const float*)d_in[10];
  const float* Wo = (const float*)d_in[11];
  const float* bo = (const float*)d_in[12];
  float* out = (float*)d_out;

  const size_t MB = 1ull << 20;
  char* ws = (char*)d_ws;
  u16* WT = (u16*)ws;                     // 48MB: Wqkv^T bf16; Wo^T overwrites after QKV GEMM
  u16* Xb = (u16*)(ws + 48 * MB);         // 16MB: X bf16 (dead after QKV GEMM); attnO reuses
  u16* attnO = Xb;
  u16* Qs = (u16*)(ws + 64 * MB);         // 16MB: Q [32][2048][128]
  u16* Kfr = (u16*)(ws + 88 * MB);        // 4MB: K fragment-packed
  u16* Vfr = (u16*)(ws + 92 * MB);        // 4MB: V fragment-packed
  float* bqkv = (float*)(ws + 96 * MB);   // 24KB

  // prep: conv + Wq/Wk/Wv transposes + bias concat
  prep_k<<<10264, 256, 0, stream>>>(X, Wq, Wk, Wv, bq, bk, bv, Xb, WT, bqkv);

  // QKV GEMM (128x384 tiles, 256 WGs = 100% CU coverage) + fused RoPE/scatter epilogue
  gemmqkv_k<<<256, 512, 0, stream>>>(Xb, WT, bqkv, pos, cosT, sinT, Qs, Kfr, Vfr, 4096);

  // attn (512 blocks) + Wo^T transpose (4096 blocks, overlaps attn tail)
  attnwot_k<<<4608, 256, 0, stream>>>(Qs, Kfr, Vfr, attnO, Wo, WT);

  // out-proj: 128x128 tiles, 512 WGs
  gemm4_k<128, 128, 3, float><<<512, 256, 0, stream>>>(attnO, WT, bo, out, 2048, 4096, 4096);
}